// Round 1
// baseline (804.222 us; speedup 1.0000x reference)
//
#include <hip/hip_runtime.h>

#define NSRC   100000
#define NDST0  30000
#define NDST1  8000
#define E0N    200000
#define E1N    80000
#define HD     256   // H*D
#define DD     64
#define CAP    64    // max edges per dst bucket (lambda ~6.7, overflow prob ~0)

static __device__ __forceinline__ void fma4(float4& a, float s, const float4& b) {
    a.x = fmaf(s, b.x, a.x);
    a.y = fmaf(s, b.y, a.y);
    a.z = fmaf(s, b.z, a.z);
    a.w = fmaf(s, b.w, a.w);
}

// Wl[k][h] = sum_d W[k][h*64+d]*al[h][d] ; Wr likewise with ar.
__global__ void k_prep_wlr(const float* __restrict__ W, const float* __restrict__ al,
                           const float* __restrict__ ar, float* __restrict__ wl,
                           float* __restrict__ wr, int K)
{
    int tid = blockIdx.x * blockDim.x + threadIdx.x;
    if (tid >= K * 4) return;
    int k = tid >> 2, h = tid & 3;
    const float* wrow = W + (size_t)k * HD + h * DD;
    const float* a_l = al + h * DD;
    const float* a_r = ar + h * DD;
    float sl = 0.f, sr = 0.f;
    for (int d = 0; d < DD; ++d) {
        float w = wrow[d];
        sl = fmaf(w, a_l[d], sl);
        sr = fmaf(w, a_r[d], sr);
    }
    wl[k * 4 + h] = sl;
    wr[k * 4 + h] = sr;
}

// Z[M x 256] = X[M x K] @ W[K x 256].  Block: 256 thr, 32 rows; thread owns 4 cols x 8 rows.
template<int K>
__global__ __launch_bounds__(256) void k_gemm_z(const float* __restrict__ X,
                                                const float* __restrict__ W,
                                                float* __restrict__ Z, int M)
{
    __shared__ float xs[32 * K];
    const int r0 = blockIdx.x * 32;
    const int t = threadIdx.x;
    int rows = M - r0; if (rows > 32) rows = 32;
    const int lim4 = rows * K / 4;
    const float4* Xv = reinterpret_cast<const float4*>(X + (size_t)r0 * K);
    float4* xsv = reinterpret_cast<float4*>(xs);
    for (int i = t; i < 32 * K / 4; i += 256)
        xsv[i] = (i < lim4) ? Xv[i] : make_float4(0.f, 0.f, 0.f, 0.f);
    __syncthreads();

    const int tx = t & 63, ty = t >> 6;
    const int c0 = tx * 4;
    float4 acc[8];
    #pragma unroll
    for (int r = 0; r < 8; ++r) acc[r] = make_float4(0.f, 0.f, 0.f, 0.f);
    const float* xrow = xs + (ty * 8) * K;
    #pragma unroll 4
    for (int k4 = 0; k4 < K; k4 += 4) {
        float4 w0 = *reinterpret_cast<const float4*>(W + (size_t)(k4 + 0) * HD + c0);
        float4 w1 = *reinterpret_cast<const float4*>(W + (size_t)(k4 + 1) * HD + c0);
        float4 w2 = *reinterpret_cast<const float4*>(W + (size_t)(k4 + 2) * HD + c0);
        float4 w3 = *reinterpret_cast<const float4*>(W + (size_t)(k4 + 3) * HD + c0);
        #pragma unroll
        for (int r = 0; r < 8; ++r) {
            float4 xv = *reinterpret_cast<const float4*>(&xrow[r * K + k4]);
            fma4(acc[r], xv.x, w0);
            fma4(acc[r], xv.y, w1);
            fma4(acc[r], xv.z, w2);
            fma4(acc[r], xv.w, w3);
        }
    }
    #pragma unroll
    for (int r = 0; r < 8; ++r) {
        int row = r0 + ty * 8 + r;
        if (row < M)
            *reinterpret_cast<float4*>(Z + (size_t)row * HD + c0) = acc[r];
    }
}

// out[M x 4] = X[M x K] @ Wv[K x 4]   (el / er)
template<int K>
__global__ __launch_bounds__(256) void k_gemv4(const float* __restrict__ X,
                                               const float* __restrict__ Wv,
                                               float* __restrict__ out, int M)
{
    int row = blockIdx.x * blockDim.x + threadIdx.x;
    if (row >= M) return;
    const float4* xv = reinterpret_cast<const float4*>(X + (size_t)row * K);
    const float4* wv = reinterpret_cast<const float4*>(Wv);
    float4 acc = make_float4(0.f, 0.f, 0.f, 0.f);
    #pragma unroll
    for (int k4 = 0; k4 < K / 4; ++k4) {
        float4 x = xv[k4];
        fma4(acc, x.x, wv[k4 * 4 + 0]);
        fma4(acc, x.y, wv[k4 * 4 + 1]);
        fma4(acc, x.z, wv[k4 * 4 + 2]);
        fma4(acc, x.w, wv[k4 * 4 + 3]);
    }
    *reinterpret_cast<float4*>(out + (size_t)row * 4) = acc;
}

// Bucket edges by dst (order within a dst is arbitrary; softmax-weighted sum is order-robust).
__global__ void k_fill(const int* __restrict__ edst, int* __restrict__ count,
                       int* __restrict__ eids, int E)
{
    int e = blockIdx.x * blockDim.x + threadIdx.x;
    if (e >= E) return;
    int d = edst[e];
    int c = atomicAdd(&count[d], 1);
    if (c < CAP) eids[(size_t)d * CAP + c] = e;
}

// One wave per dst: out[dst,h,:] = sum_e ex * z[src_e] / sum_e ex ; ex = exp(lrelu(el[src]+er[dst]))
__global__ __launch_bounds__(256) void k_agg(const int* __restrict__ count,
                                             const int* __restrict__ eids,
                                             const int* __restrict__ esrc,
                                             const float* __restrict__ el,
                                             const float* __restrict__ er,
                                             const float* __restrict__ z,
                                             float* __restrict__ out, int ndst)
{
    int wid = (blockIdx.x * blockDim.x + threadIdx.x) >> 6;
    int lane = threadIdx.x & 63;
    if (wid >= ndst) return;
    int h = lane >> 4;                       // 16 lanes per head, 4 cols each
    int cnt = count[wid]; if (cnt > CAP) cnt = CAP;
    float erv = er[wid * 4 + h];
    float4 acc = make_float4(0.f, 0.f, 0.f, 0.f);
    float den = 0.f;
    const int* lst = eids + (size_t)wid * CAP;
    for (int i = 0; i < cnt; ++i) {
        int e = lst[i];
        int s = esrc[e];
        float ev = el[s * 4 + h] + erv;
        ev = ev > 0.f ? ev : 0.2f * ev;      // LeakyReLU(0.2)
        float ex = __expf(ev);               // no max-shift needed: softmax is shift-invariant
        float4 zv = *reinterpret_cast<const float4*>(z + (size_t)s * HD + lane * 4);
        den += ex;
        fma4(acc, ex, zv);
    }
    float inv = den > 0.f ? 1.f / den : 0.f;
    acc.x *= inv; acc.y *= inv; acc.z *= inv; acc.w *= inv;
    *reinterpret_cast<float4*>(out + (size_t)wid * HD + lane * 4) = acc;
}

// Self-attention pool over S slots + mean, plus copy of base features into dst row.
// feat[s] = src[n,s,:] + bias[s,:]; scores = feat@feat^T/8; softmax(axis=t); out=(p@feat).mean(s)
template<int S>
__global__ __launch_bounds__(256) void k_pool(const float* __restrict__ srcA,
                                              const float* __restrict__ bA,
                                              const float* __restrict__ srcB,
                                              const float* __restrict__ bB,
                                              const float* __restrict__ base, int baseCols,
                                              float* __restrict__ dst, int pitch, int colOff,
                                              int n)
{
    int wid = (blockIdx.x * blockDim.x + threadIdx.x) >> 6;
    int lane = threadIdx.x & 63;
    if (wid >= n) return;
    float f[S];
    #pragma unroll
    for (int s = 0; s < S; ++s) {
        if (s < 4) f[s] = srcA[(size_t)wid * HD + s * DD + lane] + bA[s * DD + lane];
        else       f[s] = srcB[(size_t)wid * HD + (s - 4) * DD + lane] + bB[(s - 4) * DD + lane];
    }
    float ps[S * S];
    #pragma unroll
    for (int s = 0; s < S; ++s)
        #pragma unroll
        for (int t = 0; t < S; ++t) ps[s * S + t] = f[s] * f[t];
    #pragma unroll
    for (int off = 1; off < 64; off <<= 1) {
        #pragma unroll
        for (int i = 0; i < S * S; ++i) ps[i] += __shfl_xor(ps[i], off, 64);
    }
    float g[S];
    #pragma unroll
    for (int t = 0; t < S; ++t) g[t] = 0.f;
    #pragma unroll
    for (int s = 0; s < S; ++s) {
        float m = -1e30f;
        #pragma unroll
        for (int t = 0; t < S; ++t) { float v = ps[s * S + t] * 0.125f; m = v > m ? v : m; }
        float pe[S];
        float sum = 0.f;
        #pragma unroll
        for (int t = 0; t < S; ++t) { pe[t] = __expf(ps[s * S + t] * 0.125f - m); sum += pe[t]; }
        float inv = 1.f / sum;
        #pragma unroll
        for (int t = 0; t < S; ++t) g[t] += pe[t] * inv;
    }
    float o = 0.f;
    #pragma unroll
    for (int t = 0; t < S; ++t) o = fmaf(g[t], f[t], o);
    o *= (1.f / S);
    for (int c = lane; c < baseCols; c += 64)
        dst[(size_t)wid * pitch + c] = base[(size_t)wid * baseCols + c];
    dst[(size_t)wid * pitch + colOff + lane] = o;
}

extern "C" void kernel_launch(void* const* d_in, const int* in_sizes, int n_in,
                              void* d_out, int out_size, void* d_ws, size_t ws_size,
                              hipStream_t stream)
{
    const float* x_user = (const float*)d_in[0];
    const float* x_item = (const float*)d_in[1];
    // relation order in arrays: 0=e0_ii 1=e0_iu 2=e0_ui 3=e1_ii 4=e1_iu 5=e1_ui
    const int* e_s[6] = { (const int*)d_in[2], (const int*)d_in[4], (const int*)d_in[6],
                          (const int*)d_in[8], (const int*)d_in[10], (const int*)d_in[12] };
    const int* e_d[6] = { (const int*)d_in[3], (const int*)d_in[5], (const int*)d_in[7],
                          (const int*)d_in[9], (const int*)d_in[11], (const int*)d_in[13] };
    const float* W0  = (const float*)d_in[14];
    const float* al0 = (const float*)d_in[15];
    const float* ar0 = (const float*)d_in[16];
    const float* b0  = (const float*)d_in[17];
    const float* W1  = (const float*)d_in[18];
    const float* al1 = (const float*)d_in[19];
    const float* ar1 = (const float*)d_in[20];
    const float* b1  = (const float*)d_in[21];
    float* out = (float*)d_out;
    (void)in_sizes; (void)n_in; (void)out_size; (void)ws_size;

    char* p = (char*)d_ws;
    auto take = [&](size_t bytes) { char* r = p; p += (bytes + 255) & ~(size_t)255; return r; };
    float* z    = (float*)take((size_t)NSRC * HD * 4);      // 102.4 MB
    float* outA = (float*)take((size_t)NDST0 * HD * 4);     // 30.7 MB
    float* outB = (float*)take((size_t)NDST0 * HD * 4);     // 30.7 MB
    float* el   = (float*)take((size_t)NSRC * 4 * 4);
    float* er   = (float*)take((size_t)NDST0 * 4 * 4);
    int*   cnt  = (int*)take((size_t)NDST0 * 4);
    int*   eids = (int*)take((size_t)NDST0 * CAP * 4);      // 7.7 MB
    float* xu1  = (float*)take((size_t)NDST0 * 128 * 4);
    float* xi1  = (float*)take((size_t)NDST0 * 128 * 4);
    float* wl   = (float*)take(128 * 4 * 4);
    float* wr   = (float*)take(128 * 4 * 4);
    // total ~205 MB of d_ws

    auto rel = [&](int K, const float* Xs, int Ms, const float* Xd, int nd,
                   const int* es, const int* ed, int E,
                   const float* W, const float* al, const float* ar, float* ob) {
        k_prep_wlr<<<(K * 4 + 255) / 256, 256, 0, stream>>>(W, al, ar, wl, wr, K);
        if (K == 64) {
            k_gemm_z<64><<<(Ms + 31) / 32, 256, 0, stream>>>(Xs, W, z, Ms);
            k_gemv4<64><<<(Ms + 255) / 256, 256, 0, stream>>>(Xs, wl, el, Ms);
            k_gemv4<64><<<(nd + 255) / 256, 256, 0, stream>>>(Xd, wr, er, nd);
        } else {
            k_gemm_z<128><<<(Ms + 31) / 32, 256, 0, stream>>>(Xs, W, z, Ms);
            k_gemv4<128><<<(Ms + 255) / 256, 256, 0, stream>>>(Xs, wl, el, Ms);
            k_gemv4<128><<<(nd + 255) / 256, 256, 0, stream>>>(Xd, wr, er, nd);
        }
        hipMemsetAsync(cnt, 0, (size_t)nd * 4, stream);
        k_fill<<<(E + 255) / 256, 256, 0, stream>>>(ed, cnt, eids, E);
        k_agg<<<(nd + 3) / 4, 256, 0, stream>>>(cnt, eids, es, el, er, z, ob, nd);
    };

    // ---------------- layer 1 (K=64) ----------------
    // iu: src=x_item, dst=x_user[:30000]
    rel(64, x_item, NSRC, x_user, NDST0, e_s[1], e_d[1], E0N,
        W0 + 1 * 64 * HD, al0 + 256, ar0 + 256, outB);
    k_pool<4><<<(NDST0 + 3) / 4, 256, 0, stream>>>(outB, b0 + 256, outB, b0 + 256,
                                                   x_user, 64, xu1, 128, 64, NDST0);
    // ii: src=x_item, dst=x_item[:30000]
    rel(64, x_item, NSRC, x_item, NDST0, e_s[0], e_d[0], E0N,
        W0, al0, ar0, outA);
    // ui: src=x_user, dst=x_item[:30000]
    rel(64, x_user, NSRC, x_item, NDST0, e_s[2], e_d[2], E0N,
        W0 + 2 * 64 * HD, al0 + 512, ar0 + 512, outB);
    k_pool<8><<<(NDST0 + 3) / 4, 256, 0, stream>>>(outA, b0, outB, b0 + 512,
                                                   x_item, 64, xi1, 128, 64, NDST0);

    // ---------------- layer 2 (K=128) ----------------
    // iu: src=xi1, dst=xu1[:8000]
    rel(128, xi1, NDST0, xu1, NDST1, e_s[4], e_d[4], E1N,
        W1 + 1 * 128 * HD, al1 + 256, ar1 + 256, outB);
    k_pool<4><<<(NDST1 + 3) / 4, 256, 0, stream>>>(outB, b1 + 256, outB, b1 + 256,
                                                   xu1, 128, out, 192, 128, NDST1);
    // ii: src=xi1, dst=xi1[:8000]
    rel(128, xi1, NDST0, xi1, NDST1, e_s[3], e_d[3], E1N,
        W1, al1, ar1, outA);
    // ui: src=xu1, dst=xi1[:8000]
    rel(128, xu1, NDST0, xi1, NDST1, e_s[5], e_d[5], E1N,
        W1 + 2 * 128 * HD, al1 + 512, ar1 + 512, outB);
    k_pool<8><<<(NDST1 + 3) / 4, 256, 0, stream>>>(outA, b1, outB, b1 + 512,
                                                   xi1, 128, out + (size_t)NDST1 * 192, 192, 128, NDST1);
}

// Round 2
// 697.858 us; speedup vs baseline: 1.1524x; 1.1524x over previous
//
#include <hip/hip_runtime.h>

#define NSRC   100000
#define NDST0  30000
#define NDST1  8000
#define E0N    200000
#define E1N    80000
#define HD     256   // H*D
#define DD     64
#define CAP    64

typedef short bf16x8 __attribute__((ext_vector_type(8)));
typedef float f32x4  __attribute__((ext_vector_type(4)));

static __device__ __forceinline__ unsigned short f2bf(float f) {
    unsigned u = __float_as_uint(f);
    u += 0x7fffu + ((u >> 16) & 1u);           // RNE
    return (unsigned short)(u >> 16);
}
static __device__ __forceinline__ unsigned pack2(float a, float b) {
    return (unsigned)f2bf(a) | ((unsigned)f2bf(b) << 16);
}
static __device__ __forceinline__ void fma4(float4& a, float s, const float4& b) {
    a.x = fmaf(s, b.x, a.x); a.y = fmaf(s, b.y, a.y);
    a.z = fmaf(s, b.z, a.z); a.w = fmaf(s, b.w, a.w);
}
static __device__ __forceinline__ float dot4(const float4& a, const float4& b) {
    return fmaf(a.x, b.x, fmaf(a.y, b.y, fmaf(a.z, b.z, a.w * b.w)));
}

// Wl[k][h] = sum_d W[k][h*64+d]*al[h][d] ; Wr likewise with ar.
__global__ void k_prep_wlr(const float* __restrict__ W, const float* __restrict__ al,
                           const float* __restrict__ ar, float* __restrict__ wl,
                           float* __restrict__ wr, int K)
{
    int tid = blockIdx.x * blockDim.x + threadIdx.x;
    if (tid >= K * 4) return;
    int k = tid >> 2, h = tid & 3;
    const float* wrow = W + (size_t)k * HD + h * DD;
    const float* a_l = al + h * DD;
    const float* a_r = ar + h * DD;
    float sl = 0.f, sr = 0.f;
    for (int d = 0; d < DD; ++d) {
        float w = wrow[d];
        sl = fmaf(w, a_l[d], sl);
        sr = fmaf(w, a_r[d], sr);
    }
    wl[k * 4 + h] = sl;
    wr[k * 4 + h] = sr;
}

// Layer-1 fused prep: X(f32, Mx64) -> Xb(bf16) + el for up to 2 rels + er (rows<nd) for up to 2 rels.
__global__ __launch_bounds__(256) void k_prep_x(const float* __restrict__ X, int M, int nd,
                                                const float* __restrict__ wlA, const float* __restrict__ wlB,
                                                const float* __restrict__ wrA, const float* __restrict__ wrB,
                                                unsigned short* __restrict__ Xb,
                                                float* __restrict__ elA, float* __restrict__ elB,
                                                float* __restrict__ erA, float* __restrict__ erB)
{
    int row = blockIdx.x * blockDim.x + threadIdx.x;
    if (row >= M) return;
    float f[64];
    const float4* xv = reinterpret_cast<const float4*>(X + (size_t)row * 64);
    #pragma unroll
    for (int j = 0; j < 16; ++j) {
        float4 v = xv[j];
        f[j * 4 + 0] = v.x; f[j * 4 + 1] = v.y; f[j * 4 + 2] = v.z; f[j * 4 + 3] = v.w;
    }
    uint4* xbv = reinterpret_cast<uint4*>(Xb + (size_t)row * 64);
    #pragma unroll
    for (int j = 0; j < 8; ++j) {
        uint4 o;
        o.x = pack2(f[j * 8 + 0], f[j * 8 + 1]);
        o.y = pack2(f[j * 8 + 2], f[j * 8 + 3]);
        o.z = pack2(f[j * 8 + 4], f[j * 8 + 5]);
        o.w = pack2(f[j * 8 + 6], f[j * 8 + 7]);
        xbv[j] = o;
    }
    const float4* wlAv = reinterpret_cast<const float4*>(wlA);
    const float4* wlBv = reinterpret_cast<const float4*>(wlB);
    float4 aA = make_float4(0.f, 0.f, 0.f, 0.f), aB = aA;
    #pragma unroll 8
    for (int k = 0; k < 64; ++k) {
        float xk = f[k];
        fma4(aA, xk, wlAv[k]);
        if (elB) fma4(aB, xk, wlBv[k]);
    }
    *reinterpret_cast<float4*>(elA + (size_t)row * 4) = aA;
    if (elB) *reinterpret_cast<float4*>(elB + (size_t)row * 4) = aB;
    if (row < nd) {
        const float4* wrAv = reinterpret_cast<const float4*>(wrA);
        const float4* wrBv = reinterpret_cast<const float4*>(wrB);
        float4 rA = make_float4(0.f, 0.f, 0.f, 0.f), rB = rA;
        #pragma unroll 8
        for (int k = 0; k < 64; ++k) {
            float xk = f[k];
            fma4(rA, xk, wrAv[k]);
            if (erB) fma4(rB, xk, wrBv[k]);
        }
        *reinterpret_cast<float4*>(erA + (size_t)row * 4) = rA;
        if (erB) *reinterpret_cast<float4*>(erB + (size_t)row * 4) = rB;
    }
}

// W (Kx256 f32) -> Wt (256xK bf16). One block of 256 threads; thread owns a column.
template<int K>
__global__ void k_wt(const float* __restrict__ W, unsigned short* __restrict__ Wt)
{
    int c = threadIdx.x;
    #pragma unroll
    for (int k = 0; k < K; k += 2) {
        float a = W[(size_t)k * HD + c];
        float b = W[(size_t)(k + 1) * HD + c];
        *reinterpret_cast<unsigned*>(Wt + (size_t)c * K + k) = pack2(a, b);
    }
}

// Zb[Mx256] bf16 = Xb[MxK] bf16 @ W (via Wt=W^T, 256xK bf16). MFMA 16x16x32.
// Block = 4 waves; block tile 16 rows x 256 cols (wave wv owns cols wv*64..+63).
template<int K>
__global__ __launch_bounds__(256) void k_gemm_mfma(const unsigned short* __restrict__ Xb,
                                                   const unsigned short* __restrict__ Wt,
                                                   unsigned short* __restrict__ Zb, int M)
{
    const int lane = threadIdx.x & 63;
    const int wv = threadIdx.x >> 6;
    const int r0 = blockIdx.x * 16;
    const int rr = lane & 15, kg = lane >> 4;
    f32x4 acc[4] = {{0.f,0.f,0.f,0.f},{0.f,0.f,0.f,0.f},{0.f,0.f,0.f,0.f},{0.f,0.f,0.f,0.f}};
    const unsigned short* xp = Xb + (size_t)(r0 + rr) * K + kg * 8;
    #pragma unroll
    for (int kb = 0; kb < K; kb += 32) {
        bf16x8 a = *reinterpret_cast<const bf16x8*>(xp + kb);
        #pragma unroll
        for (int n = 0; n < 4; ++n) {
            const unsigned short* wp = Wt + (size_t)(wv * 64 + n * 16 + rr) * K + kb + kg * 8;
            bf16x8 b = *reinterpret_cast<const bf16x8*>(wp);
            acc[n] = __builtin_amdgcn_mfma_f32_16x16x32_bf16(a, b, acc[n], 0, 0, 0);
        }
    }
    #pragma unroll
    for (int n = 0; n < 4; ++n) {
        #pragma unroll
        for (int i = 0; i < 4; ++i) {
            int row = r0 + kg * 4 + i;
            Zb[(size_t)row * HD + wv * 64 + n * 16 + rr] = f2bf(acc[n][i]);
        }
    }
}

// out[M x 4] = X[M x K] @ Wv[K x 4]   (layer-2 el / er)
template<int K>
__global__ __launch_bounds__(256) void k_gemv4(const float* __restrict__ X,
                                               const float* __restrict__ Wv,
                                               float* __restrict__ out, int M)
{
    int row = blockIdx.x * blockDim.x + threadIdx.x;
    if (row >= M) return;
    const float4* xv = reinterpret_cast<const float4*>(X + (size_t)row * K);
    const float4* wv = reinterpret_cast<const float4*>(Wv);
    float4 acc = make_float4(0.f, 0.f, 0.f, 0.f);
    #pragma unroll
    for (int k4 = 0; k4 < K / 4; ++k4) {
        float4 x = xv[k4];
        fma4(acc, x.x, wv[k4 * 4 + 0]);
        fma4(acc, x.y, wv[k4 * 4 + 1]);
        fma4(acc, x.z, wv[k4 * 4 + 2]);
        fma4(acc, x.w, wv[k4 * 4 + 3]);
    }
    *reinterpret_cast<float4*>(out + (size_t)row * 4) = acc;
}

__global__ void k_fill(const int* __restrict__ edst, int* __restrict__ count,
                       int* __restrict__ eids, int E)
{
    int e = blockIdx.x * blockDim.x + threadIdx.x;
    if (e >= E) return;
    int d = edst[e];
    int c = atomicAdd(&count[d], 1);
    if (c < CAP) eids[(size_t)d * CAP + c] = e;
}

// One wave per dst: out[dst,:] = sum_e ex*z[src_e] / sum_e ex (z in bf16).
__global__ __launch_bounds__(256) void k_agg(const int* __restrict__ count,
                                             const int* __restrict__ eids,
                                             const int* __restrict__ esrc,
                                             const float* __restrict__ el,
                                             const float* __restrict__ er,
                                             const unsigned short* __restrict__ z,
                                             float* __restrict__ out, int ndst)
{
    int wid = (blockIdx.x * blockDim.x + threadIdx.x) >> 6;
    int lane = threadIdx.x & 63;
    if (wid >= ndst) return;
    int h = lane >> 4;                       // d0 = lane*4 -> head = lane/16
    int cnt = count[wid]; if (cnt > CAP) cnt = CAP;
    float erv = er[wid * 4 + h];
    float4 acc = make_float4(0.f, 0.f, 0.f, 0.f);
    float den = 0.f;
    const int* lst = eids + (size_t)wid * CAP;
    for (int i = 0; i < cnt; ++i) {
        int e = lst[i];
        int s = esrc[e];
        float ev = el[(size_t)s * 4 + h] + erv;
        ev = ev > 0.f ? ev : 0.2f * ev;
        float ex = __expf(ev);               // shift-invariant softmax: no max needed
        uint2 zv = *reinterpret_cast<const uint2*>(z + (size_t)s * HD + lane * 4);
        float z0 = __uint_as_float(zv.x << 16);
        float z1 = __uint_as_float(zv.x & 0xffff0000u);
        float z2 = __uint_as_float(zv.y << 16);
        float z3 = __uint_as_float(zv.y & 0xffff0000u);
        den += ex;
        acc.x = fmaf(ex, z0, acc.x);
        acc.y = fmaf(ex, z1, acc.y);
        acc.z = fmaf(ex, z2, acc.z);
        acc.w = fmaf(ex, z3, acc.w);
    }
    float inv = den > 0.f ? 1.f / den : 0.f;
    acc.x *= inv; acc.y *= inv; acc.z *= inv; acc.w *= inv;
    *reinterpret_cast<float4*>(out + (size_t)wid * HD + lane * 4) = acc;
}

// Attention pool: 4 nodes per wave, 16 lanes per node (lane owns 4 dims).
// Gram via symmetry (S*(S+1)/2 entries), 4-step butterfly within 16-lane groups.
template<int S>
__global__ __launch_bounds__(256) void k_pool2(const float* __restrict__ srcA, const float* __restrict__ bA,
                                               const float* __restrict__ srcB, const float* __restrict__ bB,
                                               const float* __restrict__ base, int baseCols,
                                               float* __restrict__ dst, int pitch, int colOff,
                                               unsigned short* __restrict__ bdst, int n)
{
    int wid = (blockIdx.x * 256 + threadIdx.x) >> 6;
    int lane = threadIdx.x & 63;
    int node = wid * 4 + (lane >> 4);
    int q = lane & 15;
    if (node >= n) return;

    float4 f[S];
    #pragma unroll
    for (int s = 0; s < S; ++s) {
        const float* sp = (s < 4) ? (srcA + (size_t)node * HD + s * DD)
                                  : (srcB + (size_t)node * HD + (s - 4) * DD);
        const float* bp = (s < 4) ? (bA + s * DD) : (bB + (s - 4) * DD);
        float4 v = *reinterpret_cast<const float4*>(sp + q * 4);
        float4 b = *reinterpret_cast<const float4*>(bp + q * 4);
        v.x += b.x; v.y += b.y; v.z += b.z; v.w += b.w;
        f[s] = v;
    }
    constexpr int NE = S * (S + 1) / 2;
    float gt[NE];
    {
        int idx = 0;
        #pragma unroll
        for (int s = 0; s < S; ++s)
            #pragma unroll
            for (int t = s; t < S; ++t)
                gt[idx++] = dot4(f[s], f[t]);
    }
    #pragma unroll
    for (int m = 1; m < 16; m <<= 1) {
        #pragma unroll
        for (int i = 0; i < NE; ++i) gt[i] += __shfl_xor(gt[i], m, 16);
    }
    // G(s,t) accessor on triangular storage
    auto Gv = [&](int s, int t) -> float {
        int a = s < t ? s : t, b2 = s < t ? t : s;
        return gt[a * S - a * (a - 1) / 2 + (b2 - a)];
    };
    float g[S];
    #pragma unroll
    for (int t = 0; t < S; ++t) g[t] = 0.f;
    #pragma unroll
    for (int s = 0; s < S; ++s) {
        float sc[S];
        float m = -1e30f;
        #pragma unroll
        for (int t = 0; t < S; ++t) { sc[t] = Gv(s, t) * 0.125f; m = sc[t] > m ? sc[t] : m; }
        float pe[S];
        float sum = 0.f;
        #pragma unroll
        for (int t = 0; t < S; ++t) { pe[t] = __expf(sc[t] - m); sum += pe[t]; }
        float inv = 1.f / sum;
        #pragma unroll
        for (int t = 0; t < S; ++t) g[t] += pe[t] * inv;
    }
    float4 o = make_float4(0.f, 0.f, 0.f, 0.f);
    #pragma unroll
    for (int t = 0; t < S; ++t) fma4(o, g[t], f[t]);
    const float is = 1.f / S;
    o.x *= is; o.y *= is; o.z *= is; o.w *= is;
    *reinterpret_cast<float4*>(dst + (size_t)node * pitch + colOff + q * 4) = o;
    if (bdst) {
        uint2 p; p.x = pack2(o.x, o.y); p.y = pack2(o.z, o.w);
        *reinterpret_cast<uint2*>(bdst + (size_t)node * pitch + colOff + q * 4) = p;
    }
    for (int c = q * 4; c < baseCols; c += 64) {
        float4 v = *reinterpret_cast<const float4*>(base + (size_t)node * baseCols + c);
        *reinterpret_cast<float4*>(dst + (size_t)node * pitch + c) = v;
        if (bdst) {
            uint2 p; p.x = pack2(v.x, v.y); p.y = pack2(v.z, v.w);
            *reinterpret_cast<uint2*>(bdst + (size_t)node * pitch + c) = p;
        }
    }
}

extern "C" void kernel_launch(void* const* d_in, const int* in_sizes, int n_in,
                              void* d_out, int out_size, void* d_ws, size_t ws_size,
                              hipStream_t stream)
{
    const float* x_user = (const float*)d_in[0];
    const float* x_item = (const float*)d_in[1];
    // rel order: 0=ii 1=iu 2=ui (layer index selects e0_* / e1_*)
    const int* e_s[6] = { (const int*)d_in[2], (const int*)d_in[4], (const int*)d_in[6],
                          (const int*)d_in[8], (const int*)d_in[10], (const int*)d_in[12] };
    const int* e_d[6] = { (const int*)d_in[3], (const int*)d_in[5], (const int*)d_in[7],
                          (const int*)d_in[9], (const int*)d_in[11], (const int*)d_in[13] };
    const float* W0  = (const float*)d_in[14];
    const float* al0 = (const float*)d_in[15];
    const float* ar0 = (const float*)d_in[16];
    const float* b0  = (const float*)d_in[17];
    const float* W1  = (const float*)d_in[18];
    const float* al1 = (const float*)d_in[19];
    const float* ar1 = (const float*)d_in[20];
    const float* b1  = (const float*)d_in[21];
    float* out = (float*)d_out;
    (void)in_sizes; (void)n_in; (void)out_size; (void)ws_size;

    char* p = (char*)d_ws;
    auto take = [&](size_t bytes) { char* r = p; p += (bytes + 255) & ~(size_t)255; return r; };
    unsigned short* z    = (unsigned short*)take((size_t)NSRC * HD * 2);   // 51.2 MB
    float* outA = (float*)take((size_t)NDST0 * HD * 4);                    // 30.7 MB
    float* outB = (float*)take((size_t)NDST0 * HD * 4);                    // 30.7 MB
    unsigned short* xib = (unsigned short*)take((size_t)NSRC * DD * 2);    // 12.8 MB
    unsigned short* xub = (unsigned short*)take((size_t)NSRC * DD * 2);    // 12.8 MB
    float* xu1  = (float*)take((size_t)NDST0 * 128 * 4);                   // 15.4 MB
    float* xi1  = (float*)take((size_t)NDST0 * 128 * 4);                   // 15.4 MB
    unsigned short* xu1b = (unsigned short*)take((size_t)NDST0 * 128 * 2); // 7.7 MB
    unsigned short* xi1b = (unsigned short*)take((size_t)NDST0 * 128 * 2); // 7.7 MB
    float* el3  = (float*)take((size_t)3 * NSRC * 4 * 4);                  // 4.8 MB
    float* er3  = (float*)take((size_t)3 * NDST0 * 4 * 4);                 // 1.44 MB
    int*   cnt  = (int*)take((size_t)NDST0 * 4);
    int*   eids = (int*)take((size_t)NDST0 * CAP * 4);                     // 7.7 MB
    unsigned short* Wt = (unsigned short*)take((size_t)256 * 128 * 2);
    float* wl3  = (float*)take((size_t)3 * 512 * 4);
    float* wr3  = (float*)take((size_t)3 * 512 * 4);

    float* el_ii = el3;  float* el_iu = el3 + (size_t)NSRC * 4;  float* el_ui = el3 + (size_t)2 * NSRC * 4;
    float* er_ii = er3;  float* er_iu = er3 + (size_t)NDST0 * 4; float* er_ui = er3 + (size_t)2 * NDST0 * 4;

    // ================= layer 1 (K=64) =================
    for (int r = 0; r < 3; ++r)
        k_prep_wlr<<<1, 256, 0, stream>>>(W0 + (size_t)r * 64 * HD, al0 + r * HD, ar0 + r * HD,
                                          wl3 + r * 512, wr3 + r * 512, 64);
    // item pass: el for ii,iu; er for ii (dst=item), ui (dst=item)
    k_prep_x<<<(NSRC + 255) / 256, 256, 0, stream>>>(x_item, NSRC, NDST0,
        wl3, wl3 + 512, wr3, wr3 + 1024, xib, el_ii, el_iu, er_ii, er_ui);
    // user pass: el for ui; er for iu (dst=user)
    k_prep_x<<<(NSRC + 255) / 256, 256, 0, stream>>>(x_user, NSRC, NDST0,
        wl3 + 1024, nullptr, wr3 + 512, nullptr, xub, el_ui, nullptr, er_iu, nullptr);

    auto relL1 = [&](int r, const unsigned short* xb, const int* es, const int* ed,
                     const float* el, const float* er, float* ob) {
        k_wt<64><<<1, 256, 0, stream>>>(W0 + (size_t)r * 64 * HD, Wt);
        k_gemm_mfma<64><<<NSRC / 16, 256, 0, stream>>>(xb, Wt, z, NSRC);
        hipMemsetAsync(cnt, 0, (size_t)NDST0 * 4, stream);
        k_fill<<<(E0N + 255) / 256, 256, 0, stream>>>(ed, cnt, eids, E0N);
        k_agg<<<(NDST0 + 3) / 4, 256, 0, stream>>>(cnt, eids, es, el, er, z, ob, NDST0);
    };
    relL1(1, xib, e_s[1], e_d[1], el_iu, er_iu, outB);
    k_pool2<4><<<NDST0 / 16, 256, 0, stream>>>(outB, b0 + 256, outB, b0 + 256,
                                               x_user, 64, xu1, 128, 64, xu1b, NDST0);
    relL1(0, xib, e_s[0], e_d[0], el_ii, er_ii, outA);
    relL1(2, xub, e_s[2], e_d[2], el_ui, er_ui, outB);
    k_pool2<8><<<NDST0 / 16, 256, 0, stream>>>(outA, b0, outB, b0 + 512,
                                               x_item, 64, xi1, 128, 64, xi1b, NDST0);

    // ================= layer 2 (K=128) =================
    for (int r = 0; r < 3; ++r)
        k_prep_wlr<<<2, 256, 0, stream>>>(W1 + (size_t)r * 128 * HD, al1 + r * HD, ar1 + r * HD,
                                          wl3 + r * 512, wr3 + r * 512, 128);
    k_gemv4<128><<<(NDST0 + 255) / 256, 256, 0, stream>>>(xi1, wl3,        el_ii, NDST0);
    k_gemv4<128><<<(NDST0 + 255) / 256, 256, 0, stream>>>(xi1, wl3 + 512,  el_iu, NDST0);
    k_gemv4<128><<<(NDST0 + 255) / 256, 256, 0, stream>>>(xu1, wl3 + 1024, el_ui, NDST0);
    k_gemv4<128><<<(NDST1 + 255) / 256, 256, 0, stream>>>(xi1, wr3,        er_ii, NDST1);
    k_gemv4<128><<<(NDST1 + 255) / 256, 256, 0, stream>>>(xu1, wr3 + 512,  er_iu, NDST1);
    k_gemv4<128><<<(NDST1 + 255) / 256, 256, 0, stream>>>(xi1, wr3 + 1024, er_ui, NDST1);

    auto relL2 = [&](int r, const unsigned short* xb, const int* es, const int* ed,
                     const float* el, const float* er, float* ob) {
        k_wt<128><<<1, 256, 0, stream>>>(W1 + (size_t)r * 128 * HD, Wt);
        k_gemm_mfma<128><<<NDST0 / 16, 256, 0, stream>>>(xb, Wt, z, NDST0);
        hipMemsetAsync(cnt, 0, (size_t)NDST1 * 4, stream);
        k_fill<<<(E1N + 255) / 256, 256, 0, stream>>>(ed, cnt, eids, E1N);
        k_agg<<<(NDST1 + 3) / 4, 256, 0, stream>>>(cnt, eids, es, el, er, z, ob, NDST1);
    };
    relL2(1, xi1b, e_s[4], e_d[4], el_iu, er_iu, outB);
    k_pool2<4><<<NDST1 / 16, 256, 0, stream>>>(outB, b1 + 256, outB, b1 + 256,
                                               xu1, 128, out, 192, 128, nullptr, NDST1);
    relL2(0, xi1b, e_s[3], e_d[3], el_ii, er_ii, outA);
    relL2(2, xu1b, e_s[5], e_d[5], el_ui, er_ui, outB);
    k_pool2<8><<<NDST1 / 16, 256, 0, stream>>>(outA, b1, outB, b1 + 512,
                                               xi1, 128, out + (size_t)NDST1 * 192, 192, 128, nullptr, NDST1);
}

// Round 4
// 431.418 us; speedup vs baseline: 1.8641x; 1.6176x over previous
//
#include <hip/hip_runtime.h>

#define NSRC   100000
#define NDST0  30000
#define NDST1  8000
#define E0N    200000
#define E1N    80000
#define HD     256   // H*D
#define DD     64
#define CAP    64    // max edges per dst bucket (max expected ~25 at lambda<=10)

typedef short bf16x8 __attribute__((ext_vector_type(8)));
typedef float f32x4  __attribute__((ext_vector_type(4)));

static __device__ __forceinline__ unsigned short f2bf(float f) {
    unsigned u = __float_as_uint(f);
    u += 0x7fffu + ((u >> 16) & 1u);           // RNE
    return (unsigned short)(u >> 16);
}
static __device__ __forceinline__ unsigned pack2(float a, float b) {
    return (unsigned)f2bf(a) | ((unsigned)f2bf(b) << 16);
}
static __device__ __forceinline__ void fma4(float4& a, float s, const float4& b) {
    a.x = fmaf(s, b.x, a.x); a.y = fmaf(s, b.y, a.y);
    a.z = fmaf(s, b.z, a.z); a.w = fmaf(s, b.w, a.w);
}
static __device__ __forceinline__ float dot4(const float4& a, const float4& b) {
    return fmaf(a.x, b.x, fmaf(a.y, b.y, fmaf(a.z, b.z, a.w * b.w)));
}

// wl[r][k][h] = sum_d W[r][k][h*64+d]*al[r][h][d] ; wr likewise (ar). stride 512 floats/rel.
__global__ void k_prep_wlr_all(const float* __restrict__ W, const float* __restrict__ al,
                               const float* __restrict__ ar, float* __restrict__ wl,
                               float* __restrict__ wr, int K)
{
    int tid = blockIdx.x * blockDim.x + threadIdx.x;
    if (tid >= 3 * K * 4) return;
    int r = tid / (K * 4);
    int rem = tid - r * K * 4;
    int k = rem >> 2, h = rem & 3;
    const float* wrow = W + (size_t)r * K * HD + (size_t)k * HD + h * DD;
    const float* a_l = al + r * HD + h * DD;
    const float* a_r = ar + r * HD + h * DD;
    float sl = 0.f, sr = 0.f;
    for (int d = 0; d < DD; ++d) {
        float w = wrow[d];
        sl = fmaf(w, a_l[d], sl);
        sr = fmaf(w, a_r[d], sr);
    }
    wl[r * 512 + k * 4 + h] = sl;
    wr[r * 512 + k * 4 + h] = sr;
}

// el/er prep, spill-free: static float4 indexing, full unroll.
template<int K, bool TWO>
__global__ __launch_bounds__(256) void k_prep_x(const float* __restrict__ X, int M, int nd,
                                                const float* __restrict__ wlA, const float* __restrict__ wlB,
                                                const float* __restrict__ wrA, const float* __restrict__ wrB,
                                                float* __restrict__ elA, float* __restrict__ elB,
                                                float* __restrict__ erA, float* __restrict__ erB)
{
    int row = blockIdx.x * 256 + threadIdx.x;
    if (row >= M) return;
    const float4* xv = reinterpret_cast<const float4*>(X + (size_t)row * K);
    const float4* wlAv = reinterpret_cast<const float4*>(wlA);
    const float4* wlBv = reinterpret_cast<const float4*>(wlB);
    float4 aA = make_float4(0.f, 0.f, 0.f, 0.f), aB = aA;
    #pragma unroll
    for (int c = 0; c < K / 4; ++c) {
        float4 x4 = xv[c];
        fma4(aA, x4.x, wlAv[c * 4 + 0]); fma4(aA, x4.y, wlAv[c * 4 + 1]);
        fma4(aA, x4.z, wlAv[c * 4 + 2]); fma4(aA, x4.w, wlAv[c * 4 + 3]);
        if (TWO) {
            fma4(aB, x4.x, wlBv[c * 4 + 0]); fma4(aB, x4.y, wlBv[c * 4 + 1]);
            fma4(aB, x4.z, wlBv[c * 4 + 2]); fma4(aB, x4.w, wlBv[c * 4 + 3]);
        }
    }
    *reinterpret_cast<float4*>(elA + (size_t)row * 4) = aA;
    if (TWO) *reinterpret_cast<float4*>(elB + (size_t)row * 4) = aB;
    if (row < nd) {
        const float4* wrAv = reinterpret_cast<const float4*>(wrA);
        const float4* wrBv = reinterpret_cast<const float4*>(wrB);
        float4 rA = make_float4(0.f, 0.f, 0.f, 0.f), rB = rA;
        #pragma unroll
        for (int c = 0; c < K / 4; ++c) {
            float4 x4 = xv[c];   // L1-resident re-read keeps VGPR low
            fma4(rA, x4.x, wrAv[c * 4 + 0]); fma4(rA, x4.y, wrAv[c * 4 + 1]);
            fma4(rA, x4.z, wrAv[c * 4 + 2]); fma4(rA, x4.w, wrAv[c * 4 + 3]);
            if (TWO) {
                fma4(rB, x4.x, wrBv[c * 4 + 0]); fma4(rB, x4.y, wrBv[c * 4 + 1]);
                fma4(rB, x4.z, wrBv[c * 4 + 2]); fma4(rB, x4.w, wrBv[c * 4 + 3]);
            }
        }
        *reinterpret_cast<float4*>(erA + (size_t)row * 4) = rA;
        if (TWO) *reinterpret_cast<float4*>(erB + (size_t)row * 4) = rB;
    }
}

// W (3 x K x 256 f32) -> Wt (3 x 256 x K bf16). 1D grid: blockIdx.x = relation.
template<int K>
__global__ void k_wt_all(const float* __restrict__ W, unsigned short* __restrict__ Wt)
{
    int r = blockIdx.x;
    const float* Wr = W + (size_t)r * K * HD;
    unsigned short* Wtr = Wt + (size_t)r * 256 * K;
    int c = threadIdx.x;
    #pragma unroll 4
    for (int k = 0; k < K; k += 2) {
        float a = Wr[(size_t)k * HD + c];
        float b = Wr[(size_t)(k + 1) * HD + c];
        *reinterpret_cast<unsigned*>(Wtr + (size_t)c * K + k) = pack2(a, b);
    }
}

// Bucket edges by dst (one relation, plain args).
__global__ void k_fill(const int* __restrict__ ed, int* __restrict__ cnt,
                       int* __restrict__ eids, int E)
{
    int e = blockIdx.x * 256 + threadIdx.x;
    if (e >= E) return;
    int d = ed[e];
    int c = atomicAdd(&cnt[d], 1);
    if (c < CAP) eids[(size_t)d * CAP + c] = e;
}

// x-space aggregation: aggX[dst][h][0:K] = (sum_e alpha_h * x_src)  (bf16 out, f32 accum).
// One wave per dst; 4 head groups x 16 lanes; lane owns K/16 dims.
template<int K>
__global__ __launch_bounds__(256) void k_agg(const int* __restrict__ cnt,
                                             const int* __restrict__ eids,
                                             const int* __restrict__ esrc,
                                             const float* __restrict__ el,
                                             const float* __restrict__ er,
                                             const float* __restrict__ xsrc,
                                             unsigned short* __restrict__ aggX, int nd)
{
    constexpr int NA = K / 16;
    int wid = (blockIdx.x * 256 + threadIdx.x) >> 6;
    int lane = threadIdx.x & 63;
    if (wid >= nd) return;
    int q = lane & 15, h = lane >> 4;
    float erv = er[(size_t)wid * 4 + h];
    int c = cnt[wid]; if (c > CAP) c = CAP;
    const int* lst = eids + (size_t)wid * CAP;
    float acc[NA];
    #pragma unroll
    for (int j = 0; j < NA; ++j) acc[j] = 0.f;
    float den = 0.f;
    for (int i = 0; i < c; ++i) {
        int e = lst[i];
        int s = esrc[e];
        float ev = el[(size_t)s * 4 + h] + erv;
        ev = ev > 0.f ? ev : 0.2f * ev;          // LeakyReLU(0.2)
        float ex = __expf(ev);                   // shift-invariant softmax: no max needed
        const float4* xp = reinterpret_cast<const float4*>(xsrc + (size_t)s * K) + q * (NA / 4);
        #pragma unroll
        for (int v = 0; v < NA / 4; ++v) {
            float4 x4 = xp[v];
            acc[v * 4 + 0] = fmaf(ex, x4.x, acc[v * 4 + 0]);
            acc[v * 4 + 1] = fmaf(ex, x4.y, acc[v * 4 + 1]);
            acc[v * 4 + 2] = fmaf(ex, x4.z, acc[v * 4 + 2]);
            acc[v * 4 + 3] = fmaf(ex, x4.w, acc[v * 4 + 3]);
        }
        den += ex;
    }
    float inv = den > 0.f ? 1.f / den : 0.f;
    unsigned short* op = aggX + ((size_t)wid * 4 + h) * K + q * NA;
    unsigned buf[NA / 2];
    #pragma unroll
    for (int j = 0; j < NA / 2; ++j)
        buf[j] = pack2(acc[2 * j] * inv, acc[2 * j + 1] * inv);
    if (NA == 4) *reinterpret_cast<uint2*>(op) = make_uint2(buf[0], buf[1]);
    else         *reinterpret_cast<uint4*>(op) = make_uint4(buf[0], buf[1], buf[2], buf[3]);
}

// out[nd x 256] f32: per head h (=wave), out[:, h*64:+64] = aggX[:,h,:] @ W[:, h*64:+64].
// Block = 4 waves = 16 rows x 256 cols. MFMA 16x16x32 bf16.
template<int K>
__global__ __launch_bounds__(256) void k_gemm(const unsigned short* __restrict__ A,
                                              const unsigned short* __restrict__ Wt,
                                              float* __restrict__ outb, int nd)
{
    const int lane = threadIdx.x & 63;
    const int wv = threadIdx.x >> 6;          // = head
    const int r0 = blockIdx.x * 16;
    const int rr = lane & 15, kg = lane >> 4;
    f32x4 acc[4] = {{0.f,0.f,0.f,0.f},{0.f,0.f,0.f,0.f},{0.f,0.f,0.f,0.f},{0.f,0.f,0.f,0.f}};
    const unsigned short* ap = A + ((size_t)(r0 + rr) * 4 + wv) * K + kg * 8;
    #pragma unroll
    for (int kb = 0; kb < K; kb += 32) {
        bf16x8 a = *reinterpret_cast<const bf16x8*>(ap + kb);
        #pragma unroll
        for (int n = 0; n < 4; ++n) {
            const unsigned short* wp = Wt + (size_t)(wv * 64 + n * 16 + rr) * K + kb + kg * 8;
            bf16x8 b = *reinterpret_cast<const bf16x8*>(wp);
            acc[n] = __builtin_amdgcn_mfma_f32_16x16x32_bf16(a, b, acc[n], 0, 0, 0);
        }
    }
    #pragma unroll
    for (int n = 0; n < 4; ++n)
        #pragma unroll
        for (int i = 0; i < 4; ++i)
            outb[(size_t)(r0 + kg * 4 + i) * HD + wv * 64 + n * 16 + rr] = acc[n][i];
}

// Attention pool: 4 nodes per wave, 16 lanes per node (lane owns 4 dims).
template<int S>
__global__ __launch_bounds__(256) void k_pool2(const float* __restrict__ srcA, const float* __restrict__ bA,
                                               const float* __restrict__ srcB, const float* __restrict__ bB,
                                               const float* __restrict__ base, int baseCols,
                                               float* __restrict__ dst, int pitch, int colOff, int n)
{
    int wid = (blockIdx.x * 256 + threadIdx.x) >> 6;
    int lane = threadIdx.x & 63;
    int node = wid * 4 + (lane >> 4);
    int q = lane & 15;
    if (node >= n) return;

    float4 f[S];
    #pragma unroll
    for (int s = 0; s < S; ++s) {
        const float* sp = (s < 4) ? (srcA + (size_t)node * HD + s * DD)
                                  : (srcB + (size_t)node * HD + (s - 4) * DD);
        const float* bp = (s < 4) ? (bA + s * DD) : (bB + (s - 4) * DD);
        float4 v = *reinterpret_cast<const float4*>(sp + q * 4);
        float4 b = *reinterpret_cast<const float4*>(bp + q * 4);
        v.x += b.x; v.y += b.y; v.z += b.z; v.w += b.w;
        f[s] = v;
    }
    constexpr int NE = S * (S + 1) / 2;
    float gt[NE];
    {
        int idx = 0;
        #pragma unroll
        for (int s = 0; s < S; ++s)
            #pragma unroll
            for (int t = s; t < S; ++t)
                gt[idx++] = dot4(f[s], f[t]);
    }
    #pragma unroll
    for (int m = 1; m < 16; m <<= 1) {
        #pragma unroll
        for (int i = 0; i < NE; ++i) gt[i] += __shfl_xor(gt[i], m, 16);
    }
    auto Gv = [&](int s, int t) -> float {
        int a = s < t ? s : t, b2 = s < t ? t : s;
        return gt[a * S - a * (a - 1) / 2 + (b2 - a)];
    };
    float g[S];
    #pragma unroll
    for (int t = 0; t < S; ++t) g[t] = 0.f;
    #pragma unroll
    for (int s = 0; s < S; ++s) {
        float sc[S];
        float m = -1e30f;
        #pragma unroll
        for (int t = 0; t < S; ++t) { sc[t] = Gv(s, t) * 0.125f; m = sc[t] > m ? sc[t] : m; }
        float pe[S];
        float sum = 0.f;
        #pragma unroll
        for (int t = 0; t < S; ++t) { pe[t] = __expf(sc[t] - m); sum += pe[t]; }
        float inv = 1.f / sum;
        #pragma unroll
        for (int t = 0; t < S; ++t) g[t] += pe[t] * inv;
    }
    float4 o = make_float4(0.f, 0.f, 0.f, 0.f);
    #pragma unroll
    for (int t = 0; t < S; ++t) fma4(o, g[t], f[t]);
    const float is = 1.f / S;
    o.x *= is; o.y *= is; o.z *= is; o.w *= is;
    *reinterpret_cast<float4*>(dst + (size_t)node * pitch + colOff + q * 4) = o;
    for (int c = q * 4; c < baseCols; c += 64) {
        float4 v = *reinterpret_cast<const float4*>(base + (size_t)node * baseCols + c);
        *reinterpret_cast<float4*>(dst + (size_t)node * pitch + c) = v;
    }
}

extern "C" void kernel_launch(void* const* d_in, const int* in_sizes, int n_in,
                              void* d_out, int out_size, void* d_ws, size_t ws_size,
                              hipStream_t stream)
{
    const float* x_user = (const float*)d_in[0];
    const float* x_item = (const float*)d_in[1];
    // rel order within a layer: 0=ii 1=iu 2=ui
    const int* e_s[6] = { (const int*)d_in[2], (const int*)d_in[4], (const int*)d_in[6],
                          (const int*)d_in[8], (const int*)d_in[10], (const int*)d_in[12] };
    const int* e_d[6] = { (const int*)d_in[3], (const int*)d_in[5], (const int*)d_in[7],
                          (const int*)d_in[9], (const int*)d_in[11], (const int*)d_in[13] };
    const float* W0  = (const float*)d_in[14];
    const float* al0 = (const float*)d_in[15];
    const float* ar0 = (const float*)d_in[16];
    const float* b0  = (const float*)d_in[17];
    const float* W1  = (const float*)d_in[18];
    const float* al1 = (const float*)d_in[19];
    const float* ar1 = (const float*)d_in[20];
    const float* b1  = (const float*)d_in[21];
    float* out = (float*)d_out;
    (void)in_sizes; (void)n_in; (void)out_size; (void)ws_size;

    char* p = (char*)d_ws;
    auto take = [&](size_t bytes) { char* r = p; p += (bytes + 255) & ~(size_t)255; return r; };
    float* out_ii = (float*)take((size_t)NDST0 * HD * 4);                  // 30.7 MB
    float* out_iu = (float*)take((size_t)NDST0 * HD * 4);                  // 30.7 MB
    float* out_ui = (float*)take((size_t)NDST0 * HD * 4);                  // 30.7 MB
    float* xu1  = (float*)take((size_t)NDST0 * 128 * 4);                   // 15.4 MB
    float* xi1  = (float*)take((size_t)NDST0 * 128 * 4);                   // 15.4 MB
    unsigned short* aggX = (unsigned short*)take((size_t)3 * NDST0 * 4 * DD * 2); // 46.1 MB
    float* el3  = (float*)take((size_t)3 * NSRC * 4 * 4);                  // 4.8 MB
    float* er3  = (float*)take((size_t)3 * NDST0 * 4 * 4);                 // 1.44 MB
    int*   cnt3 = (int*)take((size_t)3 * NDST0 * 4);                       // 0.36 MB
    int*   eids3 = (int*)take((size_t)3 * NDST0 * CAP * 4);                // 23.0 MB
    unsigned short* Wt3 = (unsigned short*)take((size_t)3 * 256 * 128 * 2);
    float* wl3  = (float*)take((size_t)3 * 512 * 4);
    float* wr3  = (float*)take((size_t)3 * 512 * 4);
    // total ~199 MB (< round-1's passing 204.5 MB)

    float* el_ii = el3;  float* el_iu = el3 + (size_t)NSRC * 4;  float* el_ui = el3 + (size_t)2 * NSRC * 4;
    float* er_ii = er3;  float* er_iu = er3 + (size_t)NDST0 * 4; float* er_ui = er3 + (size_t)2 * NDST0 * 4;

    // ================= layer 1 (K=64) =================
    k_prep_wlr_all<<<3, 256, 0, stream>>>(W0, al0, ar0, wl3, wr3, 64);
    // item pass: el for ii,iu ; er for ii(dst=item), ui(dst=item)
    k_prep_x<64, true><<<(NSRC + 255) / 256, 256, 0, stream>>>(x_item, NSRC, NDST0,
        wl3, wl3 + 512, wr3, wr3 + 1024, el_ii, el_iu, er_ii, er_ui);
    // user pass: el for ui ; er for iu(dst=user)
    k_prep_x<64, false><<<(NSRC + 255) / 256, 256, 0, stream>>>(x_user, NSRC, NDST0,
        wl3 + 1024, nullptr, wr3 + 512, nullptr, el_ui, nullptr, er_iu, nullptr);
    k_wt_all<64><<<3, 256, 0, stream>>>(W0, Wt3);

    hipMemsetAsync(cnt3, 0, (size_t)3 * NDST0 * 4, stream);
    {
        const float* elp[3] = { el_ii, el_iu, el_ui };
        const float* erp[3] = { er_ii, er_iu, er_ui };
        const float* xsp[3] = { x_item, x_item, x_user };
        float*       obp[3] = { out_ii, out_iu, out_ui };
        for (int r = 0; r < 3; ++r) {
            int*  cr = cnt3 + (size_t)r * NDST0;
            int*  er_ids = eids3 + (size_t)r * NDST0 * CAP;
            k_fill<<<(E0N + 255) / 256, 256, 0, stream>>>(e_d[r], cr, er_ids, E0N);
            k_agg<64><<<(NDST0 + 3) / 4, 256, 0, stream>>>(cr, er_ids, e_s[r], elp[r], erp[r],
                xsp[r], aggX + (size_t)r * NDST0 * 4 * 64, NDST0);
            k_gemm<64><<<NDST0 / 16, 256, 0, stream>>>(aggX + (size_t)r * NDST0 * 4 * 64,
                Wt3 + (size_t)r * 256 * 64, obp[r], NDST0);
        }
    }
    k_pool2<4><<<NDST0 / 16, 256, 0, stream>>>(out_iu, b0 + 256, out_iu, b0 + 256,
                                               x_user, 64, xu1, 128, 64, NDST0);
    k_pool2<8><<<NDST0 / 16, 256, 0, stream>>>(out_ii, b0, out_ui, b0 + 512,
                                               x_item, 64, xi1, 128, 64, NDST0);

    // ================= layer 2 (K=128) =================
    k_prep_wlr_all<<<6, 256, 0, stream>>>(W1, al1, ar1, wl3, wr3, 128);
    k_prep_x<128, true><<<(NDST0 + 255) / 256, 256, 0, stream>>>(xi1, NDST0, NDST1,
        wl3, wl3 + 512, wr3, wr3 + 1024, el_ii, el_iu, er_ii, er_ui);
    k_prep_x<128, false><<<(NDST0 + 255) / 256, 256, 0, stream>>>(xu1, NDST0, NDST1,
        wl3 + 1024, nullptr, wr3 + 512, nullptr, el_ui, nullptr, er_iu, nullptr);
    k_wt_all<128><<<3, 256, 0, stream>>>(W1, Wt3);

    hipMemsetAsync(cnt3, 0, (size_t)3 * NDST1 * 4, stream);
    {
        const float* elp[3] = { el_ii, el_iu, el_ui };
        const float* erp[3] = { er_ii, er_iu, er_ui };
        const float* xsp[3] = { xi1, xi1, xu1 };
        float*       obp[3] = { out_ii, out_iu, out_ui };
        for (int r = 0; r < 3; ++r) {
            int*  cr = cnt3 + (size_t)r * NDST1;
            int*  er_ids = eids3 + (size_t)r * NDST1 * CAP;
            k_fill<<<(E1N + 255) / 256, 256, 0, stream>>>(e_d[3 + r], cr, er_ids, E1N);
            k_agg<128><<<(NDST1 + 3) / 4, 256, 0, stream>>>(cr, er_ids, e_s[3 + r], elp[r], erp[r],
                xsp[r], aggX + (size_t)r * NDST1 * 4 * 128, NDST1);
            k_gemm<128><<<NDST1 / 16, 256, 0, stream>>>(aggX + (size_t)r * NDST1 * 4 * 128,
                Wt3 + (size_t)r * 256 * 128, obp[r], NDST1);
        }
    }
    k_pool2<4><<<NDST1 / 16, 256, 0, stream>>>(out_iu, b1 + 256, out_iu, b1 + 256,
                                               xu1, 128, out, 192, 128, NDST1);
    k_pool2<8><<<NDST1 / 16, 256, 0, stream>>>(out_ii, b1, out_ui, b1 + 512,
                                               xi1, 128, out + (size_t)NDST1 * 192, 192, 128, NDST1);
}

// Round 7
// 366.590 us; speedup vs baseline: 2.1938x; 1.1768x over previous
//
#include <hip/hip_runtime.h>

#define NSRC   100000
#define NDST0  30000
#define NDST1  8000
#define E0N    200000
#define E1N    80000
#define HD     256   // H*D
#define DD     64
#define CAP    64    // max edges per dst bucket

typedef short bf16x8 __attribute__((ext_vector_type(8)));
typedef float f32x4  __attribute__((ext_vector_type(4)));

static __device__ __forceinline__ unsigned short f2bf(float f) {
    unsigned u = __float_as_uint(f);
    u += 0x7fffu + ((u >> 16) & 1u);           // RNE
    return (unsigned short)(u >> 16);
}
static __device__ __forceinline__ unsigned pack2(float a, float b) {
    return (unsigned)f2bf(a) | ((unsigned)f2bf(b) << 16);
}
static __device__ __forceinline__ void fma4(float4& a, float s, const float4& b) {
    a.x = fmaf(s, b.x, a.x); a.y = fmaf(s, b.y, a.y);
    a.z = fmaf(s, b.z, a.z); a.w = fmaf(s, b.w, a.w);
}
static __device__ __forceinline__ float dot4(const float4& a, const float4& b) {
    return fmaf(a.x, b.x, fmaf(a.y, b.y, fmaf(a.z, b.z, a.w * b.w)));
}
static __device__ __forceinline__ void red4(float4& a, int m) {
    a.x += __shfl_xor(a.x, m, 64);
    a.y += __shfl_xor(a.y, m, 64);
    a.z += __shfl_xor(a.z, m, 64);
    a.w += __shfl_xor(a.w, m, 64);
}

// wl[r][k][h] = sum_d W[r][k][h*64+d]*al[r][h][d] ; wr likewise (ar). stride 512 floats/rel.
__global__ void k_prep_wlr_all(const float* __restrict__ W, const float* __restrict__ al,
                               const float* __restrict__ ar, float* __restrict__ wl,
                               float* __restrict__ wr, int K)
{
    int tid = blockIdx.x * blockDim.x + threadIdx.x;
    if (tid >= 3 * K * 4) return;
    int r = tid / (K * 4);
    int rem = tid - r * K * 4;
    int k = rem >> 2, h = rem & 3;
    const float* wrow = W + (size_t)r * K * HD + (size_t)k * HD + h * DD;
    const float* a_l = al + r * HD + h * DD;
    const float* a_r = ar + r * HD + h * DD;
    float sl = 0.f, sr = 0.f;
    for (int d = 0; d < DD; ++d) {
        float w = wrow[d];
        sl = fmaf(w, a_l[d], sl);
        sr = fmaf(w, a_r[d], sr);
    }
    wl[r * 512 + k * 4 + h] = sl;
    wr[r * 512 + k * 4 + h] = sr;
}

// el/er prep, spill-free: static float4 indexing, full unroll.
template<int K, bool TWO>
__global__ __launch_bounds__(256) void k_prep_x(const float* __restrict__ X, int M, int nd,
                                                const float* __restrict__ wlA, const float* __restrict__ wlB,
                                                const float* __restrict__ wrA, const float* __restrict__ wrB,
                                                float* __restrict__ elA, float* __restrict__ elB,
                                                float* __restrict__ erA, float* __restrict__ erB)
{
    int row = blockIdx.x * 256 + threadIdx.x;
    if (row >= M) return;
    const float4* xv = reinterpret_cast<const float4*>(X + (size_t)row * K);
    const float4* wlAv = reinterpret_cast<const float4*>(wlA);
    const float4* wlBv = reinterpret_cast<const float4*>(wlB);
    float4 aA = make_float4(0.f, 0.f, 0.f, 0.f), aB = aA;
    #pragma unroll
    for (int c = 0; c < K / 4; ++c) {
        float4 x4 = xv[c];
        fma4(aA, x4.x, wlAv[c * 4 + 0]); fma4(aA, x4.y, wlAv[c * 4 + 1]);
        fma4(aA, x4.z, wlAv[c * 4 + 2]); fma4(aA, x4.w, wlAv[c * 4 + 3]);
        if (TWO) {
            fma4(aB, x4.x, wlBv[c * 4 + 0]); fma4(aB, x4.y, wlBv[c * 4 + 1]);
            fma4(aB, x4.z, wlBv[c * 4 + 2]); fma4(aB, x4.w, wlBv[c * 4 + 3]);
        }
    }
    *reinterpret_cast<float4*>(elA + (size_t)row * 4) = aA;
    if (TWO) *reinterpret_cast<float4*>(elB + (size_t)row * 4) = aB;
    if (row < nd) {
        const float4* wrAv = reinterpret_cast<const float4*>(wrA);
        const float4* wrBv = reinterpret_cast<const float4*>(wrB);
        float4 rA = make_float4(0.f, 0.f, 0.f, 0.f), rB = rA;
        #pragma unroll
        for (int c = 0; c < K / 4; ++c) {
            float4 x4 = xv[c];
            fma4(rA, x4.x, wrAv[c * 4 + 0]); fma4(rA, x4.y, wrAv[c * 4 + 1]);
            fma4(rA, x4.z, wrAv[c * 4 + 2]); fma4(rA, x4.w, wrAv[c * 4 + 3]);
            if (TWO) {
                fma4(rB, x4.x, wrBv[c * 4 + 0]); fma4(rB, x4.y, wrBv[c * 4 + 1]);
                fma4(rB, x4.z, wrBv[c * 4 + 2]); fma4(rB, x4.w, wrBv[c * 4 + 3]);
            }
        }
        *reinterpret_cast<float4*>(erA + (size_t)row * 4) = rA;
        if (TWO) *reinterpret_cast<float4*>(erB + (size_t)row * 4) = rB;
    }
}

// W (3 x K x 256 f32) -> Wt (3 x 256 x K bf16). blockIdx.x = relation.
template<int K>
__global__ void k_wt_all(const float* __restrict__ W, unsigned short* __restrict__ Wt)
{
    int r = blockIdx.x;
    const float* Wr = W + (size_t)r * K * HD;
    unsigned short* Wtr = Wt + (size_t)r * 256 * K;
    int c = threadIdx.x;
    #pragma unroll 4
    for (int k = 0; k < K; k += 2) {
        float a = Wr[(size_t)k * HD + c];
        float b = Wr[(size_t)(k + 1) * HD + c];
        *reinterpret_cast<unsigned*>(Wtr + (size_t)c * K + k) = pack2(a, b);
    }
}

// Bucket edges by dst; store SRC NODE directly.
__global__ void k_fill(const int* __restrict__ ed, const int* __restrict__ es,
                       int* __restrict__ cnt, int* __restrict__ bsrc, int E)
{
    int e = blockIdx.x * 256 + threadIdx.x;
    if (e >= E) return;
    int d = ed[e];
    int c = atomicAdd(&cnt[d], 1);
    if (c < CAP) bsrc[(size_t)d * CAP + c] = es[e];
}

// x-space aggregation, MLP-widened. FIX vs r5/r6: the edge loop now has a
// WAVE-UNIFORM trip count (nt = ceil(c/4), c wave-uniform) so every __shfl
// executes with all 64 lanes active -- no bpermute from exec-masked lanes.
// Only the gather/FMA is predicated by (i < c).
template<int K>
__global__ __launch_bounds__(256) void k_agg(const int* __restrict__ cnt,
                                             const int* __restrict__ bsrc,
                                             const float* __restrict__ el,
                                             const float* __restrict__ er,
                                             const float* __restrict__ xsrc,
                                             unsigned short* __restrict__ aggX, int nd)
{
    constexpr int NV = K / 64;                 // float4 chunks per lane: 1 (K=64) or 2 (K=128)
    int wid = (blockIdx.x * 256 + threadIdx.x) >> 6;
    int lane = threadIdx.x & 63;
    if (wid >= nd) return;
    int q = lane & 15, g = lane >> 4;
    int c = cnt[wid]; if (c > CAP) c = CAP;    // wave-uniform
    const int* lst = bsrc + (size_t)wid * CAP;
    float4 er4 = *reinterpret_cast<const float4*>(er + (size_t)wid * 4);

    int s_own = 0;
    float4 ex_own = make_float4(0.f, 0.f, 0.f, 0.f);
    if (lane < c) {
        s_own = lst[lane];
        float4 e4 = *reinterpret_cast<const float4*>(el + (size_t)s_own * 4);
        e4.x += er4.x; e4.y += er4.y; e4.z += er4.z; e4.w += er4.w;
        e4.x = e4.x > 0.f ? e4.x : 0.2f * e4.x;
        e4.y = e4.y > 0.f ? e4.y : 0.2f * e4.y;
        e4.z = e4.z > 0.f ? e4.z : 0.2f * e4.z;
        e4.w = e4.w > 0.f ? e4.w : 0.2f * e4.w;
        ex_own.x = __expf(e4.x); ex_own.y = __expf(e4.y);
        ex_own.z = __expf(e4.z); ex_own.w = __expf(e4.w);   // shift-invariant softmax
    }

    float4 acc[4][NV];
    #pragma unroll
    for (int h = 0; h < 4; ++h)
        #pragma unroll
        for (int v = 0; v < NV; ++v) acc[h][v] = make_float4(0.f, 0.f, 0.f, 0.f);
    float4 den = make_float4(0.f, 0.f, 0.f, 0.f);

    const int nt = (c + 3) >> 2;               // wave-uniform trip count
    for (int t = 0; t < nt; ++t) {
        int i = g + 4 * t;                     // this group's edge index (may be >= c)
        int ilane = i & 63;
        // shfls run under FULL exec (loop bound uniform): sources always valid lanes
        int   s   = __shfl(s_own,    ilane, 64);
        float ex0 = __shfl(ex_own.x, ilane, 64);
        float ex1 = __shfl(ex_own.y, ilane, 64);
        float ex2 = __shfl(ex_own.z, ilane, 64);
        float ex3 = __shfl(ex_own.w, ilane, 64);
        if (i < c) {
            const float4* xp = reinterpret_cast<const float4*>(xsrc + (size_t)s * K) + q * NV;
            #pragma unroll
            for (int v = 0; v < NV; ++v) {
                float4 x4 = xp[v];
                fma4(acc[0][v], ex0, x4);
                fma4(acc[1][v], ex1, x4);
                fma4(acc[2][v], ex2, x4);
                fma4(acc[3][v], ex3, x4);
            }
            den.x += ex0; den.y += ex1; den.z += ex2; den.w += ex3;
        }
    }
    // reduce the 4 edge-groups (lane bits 4-5); full exec here
    #pragma unroll
    for (int m = 16; m < 64; m <<= 1) {
        #pragma unroll
        for (int h = 0; h < 4; ++h)
            #pragma unroll
            for (int v = 0; v < NV; ++v) red4(acc[h][v], m);
        red4(den, m);
    }
    float invh[4];
    invh[0] = den.x > 0.f ? 1.f / den.x : 0.f;
    invh[1] = den.y > 0.f ? 1.f / den.y : 0.f;
    invh[2] = den.z > 0.f ? 1.f / den.z : 0.f;
    invh[3] = den.w > 0.f ? 1.f / den.w : 0.f;
    #pragma unroll
    for (int h = 0; h < 4; ++h) {
        unsigned short* op = aggX + ((size_t)wid * 4 + h) * K + q * 4 * NV;
        if (NV == 1) {
            uint2 w;
            w.x = pack2(acc[h][0].x * invh[h], acc[h][0].y * invh[h]);
            w.y = pack2(acc[h][0].z * invh[h], acc[h][0].w * invh[h]);
            *reinterpret_cast<uint2*>(op) = w;
        } else {
            uint4 w;
            w.x = pack2(acc[h][0].x * invh[h], acc[h][0].y * invh[h]);
            w.y = pack2(acc[h][0].z * invh[h], acc[h][0].w * invh[h]);
            w.z = pack2(acc[h][1].x * invh[h], acc[h][1].y * invh[h]);
            w.w = pack2(acc[h][1].z * invh[h], acc[h][1].w * invh[h]);
            *reinterpret_cast<uint4*>(op) = w;
        }
    }
}

// out[nd x 256] f32: per head h (=wave), out[:, h*64:+64] = aggX[:,h,:] @ W[:, h*64:+64].
// Block = 4 waves = 16 rows x 256 cols. MFMA 16x16x32 bf16.
template<int K>
__global__ __launch_bounds__(256) void k_gemm(const unsigned short* __restrict__ A,
                                              const unsigned short* __restrict__ Wt,
                                              float* __restrict__ outb, int nd)
{
    const int lane = threadIdx.x & 63;
    const int wv = threadIdx.x >> 6;          // = head
    const int r0 = blockIdx.x * 16;
    const int rr = lane & 15, kg = lane >> 4;
    f32x4 acc[4] = {{0.f,0.f,0.f,0.f},{0.f,0.f,0.f,0.f},{0.f,0.f,0.f,0.f},{0.f,0.f,0.f,0.f}};
    const unsigned short* ap = A + ((size_t)(r0 + rr) * 4 + wv) * K + kg * 8;
    #pragma unroll
    for (int kb = 0; kb < K; kb += 32) {
        bf16x8 a = *reinterpret_cast<const bf16x8*>(ap + kb);
        #pragma unroll
        for (int n = 0; n < 4; ++n) {
            const unsigned short* wp = Wt + (size_t)(wv * 64 + n * 16 + rr) * K + kb + kg * 8;
            bf16x8 b = *reinterpret_cast<const bf16x8*>(wp);
            acc[n] = __builtin_amdgcn_mfma_f32_16x16x32_bf16(a, b, acc[n], 0, 0, 0);
        }
    }
    #pragma unroll
    for (int n = 0; n < 4; ++n)
        #pragma unroll
        for (int i = 0; i < 4; ++i)
            outb[(size_t)(r0 + kg * 4 + i) * HD + wv * 64 + n * 16 + rr] = acc[n][i];
}

// Attention pool: 4 nodes per wave, 16 lanes per node (lane owns 4 dims). f32 sources.
template<int S>
__global__ __launch_bounds__(256) void k_pool2(const float* __restrict__ srcA, const float* __restrict__ bA,
                                               const float* __restrict__ srcB, const float* __restrict__ bB,
                                               const float* __restrict__ base, int baseCols,
                                               float* __restrict__ dst, int pitch, int colOff, int n)
{
    int wid = (blockIdx.x * 256 + threadIdx.x) >> 6;
    int lane = threadIdx.x & 63;
    int node = wid * 4 + (lane >> 4);
    int q = lane & 15;
    if (node >= n) return;

    float4 f[S];
    #pragma unroll
    for (int s = 0; s < S; ++s) {
        const float* sp = (s < 4) ? (srcA + (size_t)node * HD + s * DD)
                                  : (srcB + (size_t)node * HD + (s - 4) * DD);
        const float* bp = (s < 4) ? (bA + s * DD) : (bB + (s - 4) * DD);
        float4 v = *reinterpret_cast<const float4*>(sp + q * 4);
        float4 b = *reinterpret_cast<const float4*>(bp + q * 4);
        v.x += b.x; v.y += b.y; v.z += b.z; v.w += b.w;
        f[s] = v;
    }
    constexpr int NE = S * (S + 1) / 2;
    float gt[NE];
    {
        int idx = 0;
        #pragma unroll
        for (int s = 0; s < S; ++s)
            #pragma unroll
            for (int t = s; t < S; ++t)
                gt[idx++] = dot4(f[s], f[t]);
    }
    #pragma unroll
    for (int m = 1; m < 16; m <<= 1) {
        #pragma unroll
        for (int i = 0; i < NE; ++i) gt[i] += __shfl_xor(gt[i], m, 16);
    }
    auto Gv = [&](int s, int t) -> float {
        int a = s < t ? s : t, b2 = s < t ? t : s;
        return gt[a * S - a * (a - 1) / 2 + (b2 - a)];
    };
    float g[S];
    #pragma unroll
    for (int t = 0; t < S; ++t) g[t] = 0.f;
    #pragma unroll
    for (int s = 0; s < S; ++s) {
        float sc[S];
        float m = -1e30f;
        #pragma unroll
        for (int t = 0; t < S; ++t) { sc[t] = Gv(s, t) * 0.125f; m = sc[t] > m ? sc[t] : m; }
        float pe[S];
        float sum = 0.f;
        #pragma unroll
        for (int t = 0; t < S; ++t) { pe[t] = __expf(sc[t] - m); sum += pe[t]; }
        float inv = 1.f / sum;
        #pragma unroll
        for (int t = 0; t < S; ++t) g[t] += pe[t] * inv;
    }
    float4 o = make_float4(0.f, 0.f, 0.f, 0.f);
    #pragma unroll
    for (int t = 0; t < S; ++t) fma4(o, g[t], f[t]);
    const float is = 1.f / S;
    o.x *= is; o.y *= is; o.z *= is; o.w *= is;
    *reinterpret_cast<float4*>(dst + (size_t)node * pitch + colOff + q * 4) = o;
    for (int c = q * 4; c < baseCols; c += 64) {
        float4 v = *reinterpret_cast<const float4*>(base + (size_t)node * baseCols + c);
        *reinterpret_cast<float4*>(dst + (size_t)node * pitch + c) = v;
    }
}

extern "C" void kernel_launch(void* const* d_in, const int* in_sizes, int n_in,
                              void* d_out, int out_size, void* d_ws, size_t ws_size,
                              hipStream_t stream)
{
    const float* x_user = (const float*)d_in[0];
    const float* x_item = (const float*)d_in[1];
    // rel order within a layer: 0=ii 1=iu 2=ui
    const int* e_s[6] = { (const int*)d_in[2], (const int*)d_in[4], (const int*)d_in[6],
                          (const int*)d_in[8], (const int*)d_in[10], (const int*)d_in[12] };
    const int* e_d[6] = { (const int*)d_in[3], (const int*)d_in[5], (const int*)d_in[7],
                          (const int*)d_in[9], (const int*)d_in[11], (const int*)d_in[13] };
    const float* W0  = (const float*)d_in[14];
    const float* al0 = (const float*)d_in[15];
    const float* ar0 = (const float*)d_in[16];
    const float* b0  = (const float*)d_in[17];
    const float* W1  = (const float*)d_in[18];
    const float* al1 = (const float*)d_in[19];
    const float* ar1 = (const float*)d_in[20];
    const float* b1  = (const float*)d_in[21];
    float* out = (float*)d_out;
    (void)in_sizes; (void)n_in; (void)out_size; (void)ws_size;

    char* p = (char*)d_ws;
    auto take = [&](size_t bytes) { char* r = p; p += (bytes + 255) & ~(size_t)255; return r; };
    float* out_ii = (float*)take((size_t)NDST0 * HD * 4);                  // 30.7 MB
    float* out_iu = (float*)take((size_t)NDST0 * HD * 4);                  // 30.7 MB
    float* out_ui = (float*)take((size_t)NDST0 * HD * 4);                  // 30.7 MB
    float* xu1  = (float*)take((size_t)NDST0 * 128 * 4);                   // 15.4 MB
    float* xi1  = (float*)take((size_t)NDST0 * 128 * 4);                   // 15.4 MB
    unsigned short* aggX = (unsigned short*)take((size_t)3 * NDST0 * 4 * DD * 2); // 46.1 MB
    float* el3  = (float*)take((size_t)3 * NSRC * 4 * 4);                  // 4.8 MB
    float* er3  = (float*)take((size_t)3 * NDST0 * 4 * 4);                 // 1.44 MB
    int*   cnt3 = (int*)take((size_t)3 * NDST0 * 4);                       // 0.36 MB
    int*   bsrc3 = (int*)take((size_t)3 * NDST0 * CAP * 4);                // 23.0 MB
    unsigned short* Wt3 = (unsigned short*)take((size_t)3 * 256 * 128 * 2);
    float* wl3  = (float*)take((size_t)3 * 512 * 4);
    float* wr3  = (float*)take((size_t)3 * 512 * 4);
    // total ~199 MB

    float* el_ii = el3;  float* el_iu = el3 + (size_t)NSRC * 4;  float* el_ui = el3 + (size_t)2 * NSRC * 4;
    float* er_ii = er3;  float* er_iu = er3 + (size_t)NDST0 * 4; float* er_ui = er3 + (size_t)2 * NDST0 * 4;

    // ================= layer 1 (K=64) =================
    k_prep_wlr_all<<<3, 256, 0, stream>>>(W0, al0, ar0, wl3, wr3, 64);
    k_prep_x<64, true><<<(NSRC + 255) / 256, 256, 0, stream>>>(x_item, NSRC, NDST0,
        wl3, wl3 + 512, wr3, wr3 + 1024, el_ii, el_iu, er_ii, er_ui);
    k_prep_x<64, false><<<(NSRC + 255) / 256, 256, 0, stream>>>(x_user, NSRC, NDST0,
        wl3 + 1024, nullptr, wr3 + 512, nullptr, el_ui, nullptr, er_iu, nullptr);
    k_wt_all<64><<<3, 256, 0, stream>>>(W0, Wt3);

    hipMemsetAsync(cnt3, 0, (size_t)3 * NDST0 * 4, stream);
    {
        const float* elp[3] = { el_ii, el_iu, el_ui };
        const float* erp[3] = { er_ii, er_iu, er_ui };
        const float* xsp[3] = { x_item, x_item, x_user };
        float*       obp[3] = { out_ii, out_iu, out_ui };
        for (int r = 0; r < 3; ++r) {
            int* cr = cnt3 + (size_t)r * NDST0;
            int* br = bsrc3 + (size_t)r * NDST0 * CAP;
            k_fill<<<(E0N + 255) / 256, 256, 0, stream>>>(e_d[r], e_s[r], cr, br, E0N);
            k_agg<64><<<(NDST0 + 3) / 4, 256, 0, stream>>>(cr, br, elp[r], erp[r],
                xsp[r], aggX + (size_t)r * NDST0 * 4 * 64, NDST0);
            k_gemm<64><<<NDST0 / 16, 256, 0, stream>>>(aggX + (size_t)r * NDST0 * 4 * 64,
                Wt3 + (size_t)r * 256 * 64, obp[r], NDST0);
        }
    }
    k_pool2<4><<<NDST0 / 16, 256, 0, stream>>>(out_iu, b0 + 256, out_iu, b0 + 256,
                                               x_user, 64, xu1, 128, 64, NDST0);
    k_pool2<8><<<NDST0 / 16, 256, 0, stream>>>(out_ii, b0, out_ui, b0 + 512,
                                               x_item, 64, xi1, 128, 64, NDST0);

    // ================= layer 2 (K=128) =================
    k_prep_wlr_all<<<6, 256, 0, stream>>>(W1, al1, ar1, wl3, wr3, 128);
    k_prep_x<128, true><<<(NDST0 + 255) / 256, 256, 0, stream>>>(xi1, NDST0, NDST1,
        wl3, wl3 + 512, wr3, wr3 + 1024, el_ii, el_iu, er_ii, er_ui);
    k_prep_x<128, false><<<(NDST0 + 255) / 256, 256, 0, stream>>>(xu1, NDST0, NDST1,
        wl3 + 1024, nullptr, wr3 + 512, nullptr, el_ui, nullptr, er_iu, nullptr);
    k_wt_all<128><<<3, 256, 0, stream>>>(W1, Wt3);

    hipMemsetAsync(cnt3, 0, (size_t)3 * NDST1 * 4, stream);
    {
        const float* elp[3] = { el_ii, el_iu, el_ui };
        const float* erp[3] = { er_ii, er_iu, er_ui };
        const float* xsp[3] = { xi1, xi1, xu1 };
        float*       obp[3] = { out_ii, out_iu, out_ui };
        for (int r = 0; r < 3; ++r) {
            int* cr = cnt3 + (size_t)r * NDST1;
            int* br = bsrc3 + (size_t)r * NDST1 * CAP;
            k_fill<<<(E1N + 255) / 256, 256, 0, stream>>>(e_d[3 + r], e_s[3 + r], cr, br, E1N);
            k_agg<128><<<(NDST1 + 3) / 4, 256, 0, stream>>>(cr, br, elp[r], erp[r],
                xsp[r], aggX + (size_t)r * NDST1 * 4 * 128, NDST1);
            k_gemm<128><<<NDST1 / 16, 256, 0, stream>>>(aggX + (size_t)r * NDST1 * 4 * 128,
                Wt3 + (size_t)r * 256 * 128, obp[r], NDST1);
        }
    }
    k_pool2<4><<<NDST1 / 16, 256, 0, stream>>>(out_iu, b1 + 256, out_iu, b1 + 256,
                                               xu1, 128, out, 192, 128, NDST1);
    k_pool2<8><<<NDST1 / 16, 256, 0, stream>>>(out_ii, b1, out_ui, b1 + 512,
                                               xi1, 128, out + (size_t)NDST1 * 192, 192, 128, NDST1);
}

// Round 8
// 308.793 us; speedup vs baseline: 2.6044x; 1.1872x over previous
//
#include <hip/hip_runtime.h>

#define NSRC   100000
#define NDST0  30000
#define NDST1  8000
#define E0N    200000
#define E1N    80000
#define HD     256   // H*D
#define DD     64
#define CAP    64    // max edges per dst bucket

typedef short bf16x8 __attribute__((ext_vector_type(8)));
typedef float f32x4  __attribute__((ext_vector_type(4)));

static __device__ __forceinline__ unsigned short f2bf(float f) {
    unsigned u = __float_as_uint(f);
    u += 0x7fffu + ((u >> 16) & 1u);           // RNE
    return (unsigned short)(u >> 16);
}
static __device__ __forceinline__ unsigned pack2(float a, float b) {
    return (unsigned)f2bf(a) | ((unsigned)f2bf(b) << 16);
}
static __device__ __forceinline__ void fma4(float4& a, float s, const float4& b) {
    a.x = fmaf(s, b.x, a.x); a.y = fmaf(s, b.y, a.y);
    a.z = fmaf(s, b.z, a.z); a.w = fmaf(s, b.w, a.w);
}
static __device__ __forceinline__ float dot4(const float4& a, const float4& b) {
    return fmaf(a.x, b.x, fmaf(a.y, b.y, fmaf(a.z, b.z, a.w * b.w)));
}
static __device__ __forceinline__ float4 ld_bf4(const unsigned short* p) {
    uint2 u = *reinterpret_cast<const uint2*>(p);
    float4 r;
    r.x = __uint_as_float(u.x << 16);
    r.y = __uint_as_float(u.x & 0xffff0000u);
    r.z = __uint_as_float(u.y << 16);
    r.w = __uint_as_float(u.y & 0xffff0000u);
    return r;
}
static __device__ __forceinline__ void red4(float4& a, int m) {
    a.x += __shfl_xor(a.x, m, 64);
    a.y += __shfl_xor(a.y, m, 64);
    a.z += __shfl_xor(a.z, m, 64);
    a.w += __shfl_xor(a.w, m, 64);
}

// wl[r][k][h] = sum_d W[r][k][h*64+d]*al[r][h][d] ; wr likewise (ar). stride 512 floats/rel.
__global__ void k_prep_wlr_all(const float* __restrict__ W, const float* __restrict__ al,
                               const float* __restrict__ ar, float* __restrict__ wl,
                               float* __restrict__ wr, int K)
{
    int tid = blockIdx.x * blockDim.x + threadIdx.x;
    if (tid >= 3 * K * 4) return;
    int r = tid / (K * 4);
    int rem = tid - r * K * 4;
    int k = rem >> 2, h = rem & 3;
    const float* wrow = W + (size_t)r * K * HD + (size_t)k * HD + h * DD;
    const float* a_l = al + r * HD + h * DD;
    const float* a_r = ar + r * HD + h * DD;
    float sl = 0.f, sr = 0.f;
    for (int d = 0; d < DD; ++d) {
        float w = wrow[d];
        sl = fmaf(w, a_l[d], sl);
        sr = fmaf(w, a_r[d], sr);
    }
    wl[r * 512 + k * 4 + h] = sl;
    wr[r * 512 + k * 4 + h] = sr;
}

// el/er prep, spill-free: static float4 indexing, full unroll.
template<int K, bool TWO>
__global__ __launch_bounds__(256) void k_prep_x(const float* __restrict__ X, int M, int nd,
                                                const float* __restrict__ wlA, const float* __restrict__ wlB,
                                                const float* __restrict__ wrA, const float* __restrict__ wrB,
                                                float* __restrict__ elA, float* __restrict__ elB,
                                                float* __restrict__ erA, float* __restrict__ erB)
{
    int row = blockIdx.x * 256 + threadIdx.x;
    if (row >= M) return;
    const float4* xv = reinterpret_cast<const float4*>(X + (size_t)row * K);
    const float4* wlAv = reinterpret_cast<const float4*>(wlA);
    const float4* wlBv = reinterpret_cast<const float4*>(wlB);
    float4 aA = make_float4(0.f, 0.f, 0.f, 0.f), aB = aA;
    #pragma unroll
    for (int c = 0; c < K / 4; ++c) {
        float4 x4 = xv[c];
        fma4(aA, x4.x, wlAv[c * 4 + 0]); fma4(aA, x4.y, wlAv[c * 4 + 1]);
        fma4(aA, x4.z, wlAv[c * 4 + 2]); fma4(aA, x4.w, wlAv[c * 4 + 3]);
        if (TWO) {
            fma4(aB, x4.x, wlBv[c * 4 + 0]); fma4(aB, x4.y, wlBv[c * 4 + 1]);
            fma4(aB, x4.z, wlBv[c * 4 + 2]); fma4(aB, x4.w, wlBv[c * 4 + 3]);
        }
    }
    *reinterpret_cast<float4*>(elA + (size_t)row * 4) = aA;
    if (TWO) *reinterpret_cast<float4*>(elB + (size_t)row * 4) = aB;
    if (row < nd) {
        const float4* wrAv = reinterpret_cast<const float4*>(wrA);
        const float4* wrBv = reinterpret_cast<const float4*>(wrB);
        float4 rA = make_float4(0.f, 0.f, 0.f, 0.f), rB = rA;
        #pragma unroll
        for (int c = 0; c < K / 4; ++c) {
            float4 x4 = xv[c];
            fma4(rA, x4.x, wrAv[c * 4 + 0]); fma4(rA, x4.y, wrAv[c * 4 + 1]);
            fma4(rA, x4.z, wrAv[c * 4 + 2]); fma4(rA, x4.w, wrAv[c * 4 + 3]);
            if (TWO) {
                fma4(rB, x4.x, wrBv[c * 4 + 0]); fma4(rB, x4.y, wrBv[c * 4 + 1]);
                fma4(rB, x4.z, wrBv[c * 4 + 2]); fma4(rB, x4.w, wrBv[c * 4 + 3]);
            }
        }
        *reinterpret_cast<float4*>(erA + (size_t)row * 4) = rA;
        if (TWO) *reinterpret_cast<float4*>(erB + (size_t)row * 4) = rB;
    }
}

// W (3 x K x 256 f32) -> Wt (3 x 256 x K bf16). blockIdx.x = relation.
template<int K>
__global__ void k_wt_all(const float* __restrict__ W, unsigned short* __restrict__ Wt)
{
    int r = blockIdx.x;
    const float* Wr = W + (size_t)r * K * HD;
    unsigned short* Wtr = Wt + (size_t)r * 256 * K;
    int c = threadIdx.x;
    #pragma unroll 4
    for (int k = 0; k < K; k += 2) {
        float a = Wr[(size_t)k * HD + c];
        float b = Wr[(size_t)(k + 1) * HD + c];
        *reinterpret_cast<unsigned*>(Wtr + (size_t)c * K + k) = pack2(a, b);
    }
}

// Bucket edges by dst for 3 relations in one launch; store SRC NODE directly.
// Plain args + 1D grid (replay-safe style): r from blockIdx range.
__global__ void k_fill3(const int* __restrict__ ed0, const int* __restrict__ ed1,
                        const int* __restrict__ ed2, const int* __restrict__ es0,
                        const int* __restrict__ es1, const int* __restrict__ es2,
                        int* __restrict__ cnt, int* __restrict__ bsrc,
                        int E, int nd, int bpr)
{
    int bx = blockIdx.x;
    int r = (bx >= 2 * bpr) ? 2 : (bx >= bpr ? 1 : 0);
    int e = (bx - r * bpr) * 256 + threadIdx.x;
    if (e >= E) return;
    const int* ed = (r == 0) ? ed0 : (r == 1 ? ed1 : ed2);
    const int* es = (r == 0) ? es0 : (r == 1 ? es1 : es2);
    int d = ed[e];
    int c = atomicAdd(&cnt[(size_t)r * nd + d], 1);
    if (c < CAP) bsrc[((size_t)r * nd + d) * CAP + c] = es[e];
}

// x-space aggregation for 3 relations in one launch, MLP-widened, wave-uniform
// shfl loop (r7 fix). aggX[r][dst][h][0:K] = (sum_e ex_h*x_src)/sum_e ex_h (bf16).
template<int K>
__global__ __launch_bounds__(256) void k_agg3(const int* __restrict__ cnt,
                                              const int* __restrict__ bsrc,
                                              const float* __restrict__ el3,
                                              const float* __restrict__ er3,
                                              const float* __restrict__ xsA,
                                              const float* __restrict__ xsB,
                                              unsigned short* __restrict__ aggX,
                                              int nd, int bpr)
{
    constexpr int NV = K / 64;                 // float4 chunks per lane
    int bx = blockIdx.x;
    int r = (bx >= 2 * bpr) ? 2 : (bx >= bpr ? 1 : 0);
    int wid = ((bx - r * bpr) * 256 + (int)threadIdx.x) >> 6;
    int lane = threadIdx.x & 63;
    if (wid >= nd) return;
    int q = lane & 15, g = lane >> 4;
    const float* el = el3 + (size_t)r * NSRC * 4;
    const float* xsrc = (r < 2) ? xsA : xsB;
    int c = cnt[(size_t)r * nd + wid]; if (c > CAP) c = CAP;   // wave-uniform
    const int* lst = bsrc + ((size_t)r * nd + wid) * CAP;
    float4 er4 = *reinterpret_cast<const float4*>(er3 + (size_t)r * NDST0 * 4 + (size_t)wid * 4);

    int s_own = 0;
    float4 ex_own = make_float4(0.f, 0.f, 0.f, 0.f);
    if (lane < c) {
        s_own = lst[lane];
        float4 e4 = *reinterpret_cast<const float4*>(el + (size_t)s_own * 4);
        e4.x += er4.x; e4.y += er4.y; e4.z += er4.z; e4.w += er4.w;
        e4.x = e4.x > 0.f ? e4.x : 0.2f * e4.x;
        e4.y = e4.y > 0.f ? e4.y : 0.2f * e4.y;
        e4.z = e4.z > 0.f ? e4.z : 0.2f * e4.z;
        e4.w = e4.w > 0.f ? e4.w : 0.2f * e4.w;
        ex_own.x = __expf(e4.x); ex_own.y = __expf(e4.y);
        ex_own.z = __expf(e4.z); ex_own.w = __expf(e4.w);   // shift-invariant softmax
    }

    float4 acc[4][NV];
    #pragma unroll
    for (int h = 0; h < 4; ++h)
        #pragma unroll
        for (int v = 0; v < NV; ++v) acc[h][v] = make_float4(0.f, 0.f, 0.f, 0.f);
    float4 den = make_float4(0.f, 0.f, 0.f, 0.f);

    const int nt = (c + 3) >> 2;               // wave-uniform trip count
    for (int t = 0; t < nt; ++t) {
        int i = g + 4 * t;
        int ilane = i & 63;
        int   s   = __shfl(s_own,    ilane, 64);   // full-exec shfl: always valid src lane
        float ex0 = __shfl(ex_own.x, ilane, 64);
        float ex1 = __shfl(ex_own.y, ilane, 64);
        float ex2 = __shfl(ex_own.z, ilane, 64);
        float ex3 = __shfl(ex_own.w, ilane, 64);
        if (i < c) {
            const float4* xp = reinterpret_cast<const float4*>(xsrc + (size_t)s * K) + q * NV;
            #pragma unroll
            for (int v = 0; v < NV; ++v) {
                float4 x4 = xp[v];
                fma4(acc[0][v], ex0, x4);
                fma4(acc[1][v], ex1, x4);
                fma4(acc[2][v], ex2, x4);
                fma4(acc[3][v], ex3, x4);
            }
            den.x += ex0; den.y += ex1; den.z += ex2; den.w += ex3;
        }
    }
    #pragma unroll
    for (int m = 16; m < 64; m <<= 1) {
        #pragma unroll
        for (int h = 0; h < 4; ++h)
            #pragma unroll
            for (int v = 0; v < NV; ++v) red4(acc[h][v], m);
        red4(den, m);
    }
    float invh[4];
    invh[0] = den.x > 0.f ? 1.f / den.x : 0.f;
    invh[1] = den.y > 0.f ? 1.f / den.y : 0.f;
    invh[2] = den.z > 0.f ? 1.f / den.z : 0.f;
    invh[3] = den.w > 0.f ? 1.f / den.w : 0.f;
    #pragma unroll
    for (int h = 0; h < 4; ++h) {
        unsigned short* op = aggX + ((size_t)r * nd * 4 + (size_t)wid * 4 + h) * K + q * 4 * NV;
        if (NV == 1) {
            uint2 w;
            w.x = pack2(acc[h][0].x * invh[h], acc[h][0].y * invh[h]);
            w.y = pack2(acc[h][0].z * invh[h], acc[h][0].w * invh[h]);
            *reinterpret_cast<uint2*>(op) = w;
        } else {
            uint4 w;
            w.x = pack2(acc[h][0].x * invh[h], acc[h][0].y * invh[h]);
            w.y = pack2(acc[h][0].z * invh[h], acc[h][0].w * invh[h]);
            w.z = pack2(acc[h][1].x * invh[h], acc[h][1].y * invh[h]);
            w.w = pack2(acc[h][1].z * invh[h], acc[h][1].w * invh[h]);
            *reinterpret_cast<uint4*>(op) = w;
        }
    }
}

// GEMM for 3 relations in one launch. out (bf16) stride fixed NDST0*HD per rel.
// Block = 4 waves = 16 rows x 256 cols; wave = head. MFMA 16x16x32 bf16.
template<int K>
__global__ __launch_bounds__(256) void k_gemm3(const unsigned short* __restrict__ aggX,
                                               const unsigned short* __restrict__ Wt3,
                                               unsigned short* __restrict__ outb,
                                               int nd, int bpr)
{
    int bx = blockIdx.x;
    int r = (bx >= 2 * bpr) ? 2 : (bx >= bpr ? 1 : 0);
    const unsigned short* A  = aggX + (size_t)r * nd * 4 * K;
    const unsigned short* Wt = Wt3 + (size_t)r * 256 * K;
    unsigned short* ob = outb + (size_t)r * NDST0 * HD;
    const int lane = threadIdx.x & 63;
    const int wv = threadIdx.x >> 6;          // = head
    const int r0 = (bx - r * bpr) * 16;
    const int rr = lane & 15, kg = lane >> 4;
    f32x4 acc[4] = {{0.f,0.f,0.f,0.f},{0.f,0.f,0.f,0.f},{0.f,0.f,0.f,0.f},{0.f,0.f,0.f,0.f}};
    const unsigned short* ap = A + ((size_t)(r0 + rr) * 4 + wv) * K + kg * 8;
    #pragma unroll
    for (int kb = 0; kb < K; kb += 32) {
        bf16x8 a = *reinterpret_cast<const bf16x8*>(ap + kb);
        #pragma unroll
        for (int n = 0; n < 4; ++n) {
            const unsigned short* wp = Wt + (size_t)(wv * 64 + n * 16 + rr) * K + kb + kg * 8;
            bf16x8 b = *reinterpret_cast<const bf16x8*>(wp);
            acc[n] = __builtin_amdgcn_mfma_f32_16x16x32_bf16(a, b, acc[n], 0, 0, 0);
        }
    }
    #pragma unroll
    for (int n = 0; n < 4; ++n)
        #pragma unroll
        for (int i = 0; i < 4; ++i)
            ob[(size_t)(r0 + kg * 4 + i) * HD + wv * 64 + n * 16 + rr] = f2bf(acc[n][i]);
}

// Attention pool: 4 nodes per wave, 16 lanes per node (lane owns 4 dims). bf16 sources.
template<int S>
__global__ __launch_bounds__(256) void k_pool2(const unsigned short* __restrict__ srcA, const float* __restrict__ bA,
                                               const unsigned short* __restrict__ srcB, const float* __restrict__ bB,
                                               const float* __restrict__ base, int baseCols,
                                               float* __restrict__ dst, int pitch, int colOff, int n)
{
    int wid = (blockIdx.x * 256 + threadIdx.x) >> 6;
    int lane = threadIdx.x & 63;
    int node = wid * 4 + (lane >> 4);
    int q = lane & 15;
    if (node >= n) return;

    float4 f[S];
    #pragma unroll
    for (int s = 0; s < S; ++s) {
        const unsigned short* sp = (s < 4) ? (srcA + (size_t)node * HD + s * DD)
                                           : (srcB + (size_t)node * HD + (s - 4) * DD);
        const float* bp = (s < 4) ? (bA + s * DD) : (bB + (s - 4) * DD);
        float4 v = ld_bf4(sp + q * 4);
        float4 b = *reinterpret_cast<const float4*>(bp + q * 4);
        v.x += b.x; v.y += b.y; v.z += b.z; v.w += b.w;
        f[s] = v;
    }
    constexpr int NE = S * (S + 1) / 2;
    float gt[NE];
    {
        int idx = 0;
        #pragma unroll
        for (int s = 0; s < S; ++s)
            #pragma unroll
            for (int t = s; t < S; ++t)
                gt[idx++] = dot4(f[s], f[t]);
    }
    #pragma unroll
    for (int m = 1; m < 16; m <<= 1) {
        #pragma unroll
        for (int i = 0; i < NE; ++i) gt[i] += __shfl_xor(gt[i], m, 16);
    }
    auto Gv = [&](int s, int t) -> float {
        int a = s < t ? s : t, b2 = s < t ? t : s;
        return gt[a * S - a * (a - 1) / 2 + (b2 - a)];
    };
    float g[S];
    #pragma unroll
    for (int t = 0; t < S; ++t) g[t] = 0.f;
    #pragma unroll
    for (int s = 0; s < S; ++s) {
        float sc[S];
        float m = -1e30f;
        #pragma unroll
        for (int t = 0; t < S; ++t) { sc[t] = Gv(s, t) * 0.125f; m = sc[t] > m ? sc[t] : m; }
        float pe[S];
        float sum = 0.f;
        #pragma unroll
        for (int t = 0; t < S; ++t) { pe[t] = __expf(sc[t] - m); sum += pe[t]; }
        float inv = 1.f / sum;
        #pragma unroll
        for (int t = 0; t < S; ++t) g[t] += pe[t] * inv;
    }
    float4 o = make_float4(0.f, 0.f, 0.f, 0.f);
    #pragma unroll
    for (int t = 0; t < S; ++t) fma4(o, g[t], f[t]);
    const float is = 1.f / S;
    o.x *= is; o.y *= is; o.z *= is; o.w *= is;
    *reinterpret_cast<float4*>(dst + (size_t)node * pitch + colOff + q * 4) = o;
    for (int c = q * 4; c < baseCols; c += 64) {
        float4 v = *reinterpret_cast<const float4*>(base + (size_t)node * baseCols + c);
        *reinterpret_cast<float4*>(dst + (size_t)node * pitch + c) = v;
    }
}

extern "C" void kernel_launch(void* const* d_in, const int* in_sizes, int n_in,
                              void* d_out, int out_size, void* d_ws, size_t ws_size,
                              hipStream_t stream)
{
    const float* x_user = (const float*)d_in[0];
    const float* x_item = (const float*)d_in[1];
    // rel order within a layer: 0=ii 1=iu 2=ui
    const int* e_s[6] = { (const int*)d_in[2], (const int*)d_in[4], (const int*)d_in[6],
                          (const int*)d_in[8], (const int*)d_in[10], (const int*)d_in[12] };
    const int* e_d[6] = { (const int*)d_in[3], (const int*)d_in[5], (const int*)d_in[7],
                          (const int*)d_in[9], (const int*)d_in[11], (const int*)d_in[13] };
    const float* W0  = (const float*)d_in[14];
    const float* al0 = (const float*)d_in[15];
    const float* ar0 = (const float*)d_in[16];
    const float* b0  = (const float*)d_in[17];
    const float* W1  = (const float*)d_in[18];
    const float* al1 = (const float*)d_in[19];
    const float* ar1 = (const float*)d_in[20];
    const float* b1  = (const float*)d_in[21];
    float* out = (float*)d_out;
    (void)in_sizes; (void)n_in; (void)out_size; (void)ws_size;

    char* p = (char*)d_ws;
    auto take = [&](size_t bytes) { char* r = p; p += (bytes + 255) & ~(size_t)255; return r; };
    unsigned short* out3 = (unsigned short*)take((size_t)3 * NDST0 * HD * 2);  // 46.1 MB (ii|iu|ui)
    float* xu1  = (float*)take((size_t)NDST0 * 128 * 4);                       // 15.4 MB
    float* xi1  = (float*)take((size_t)NDST0 * 128 * 4);                       // 15.4 MB
    unsigned short* aggX = (unsigned short*)take((size_t)3 * NDST0 * 4 * 2 * DD * 2); // 92 MB (K up to 128)
    float* el3  = (float*)take((size_t)3 * NSRC * 4 * 4);                      // 4.8 MB
    float* er3  = (float*)take((size_t)3 * NDST0 * 4 * 4);                     // 1.44 MB
    int*   cntA = (int*)take((size_t)3 * NDST0 * 4);
    int*   cntB = (int*)take((size_t)3 * NDST1 * 4);
    int*   bsrcA = (int*)take((size_t)3 * NDST0 * CAP * 4);                    // 23.0 MB
    int*   bsrcB = (int*)take((size_t)3 * NDST1 * CAP * 4);                    // 6.1 MB
    unsigned short* Wt3 = (unsigned short*)take((size_t)3 * 256 * 128 * 2);
    float* wl3  = (float*)take((size_t)3 * 512 * 4);
    float* wr3  = (float*)take((size_t)3 * 512 * 4);
    // total ~205 MB

    unsigned short* out_ii = out3;
    unsigned short* out_iu = out3 + (size_t)NDST0 * HD;
    unsigned short* out_ui = out3 + (size_t)2 * NDST0 * HD;
    float* el_ii = el3;  float* el_iu = el3 + (size_t)NSRC * 4;  float* el_ui = el3 + (size_t)2 * NSRC * 4;
    float* er_ii = er3;  float* er_iu = er3 + (size_t)NDST0 * 4; float* er_ui = er3 + (size_t)2 * NDST0 * 4;

    // ---- bucket fills for BOTH layers, off the critical path ----
    hipMemsetAsync(cntA, 0, (size_t)3 * NDST0 * 4, stream);
    hipMemsetAsync(cntB, 0, (size_t)3 * NDST1 * 4, stream);
    {
        const int bpr0 = (E0N + 255) / 256;
        k_fill3<<<3 * bpr0, 256, 0, stream>>>(e_d[0], e_d[1], e_d[2], e_s[0], e_s[1], e_s[2],
                                              cntA, bsrcA, E0N, NDST0, bpr0);
        const int bpr1 = (E1N + 255) / 256;
        k_fill3<<<3 * bpr1, 256, 0, stream>>>(e_d[3], e_d[4], e_d[5], e_s[3], e_s[4], e_s[5],
                                              cntB, bsrcB, E1N, NDST1, bpr1);
    }

    // ================= layer 1 (K=64) =================
    k_prep_wlr_all<<<3, 256, 0, stream>>>(W0, al0, ar0, wl3, wr3, 64);
    k_prep_x<64, true><<<(NSRC + 255) / 256, 256, 0, stream>>>(x_item, NSRC, NDST0,
        wl3, wl3 + 512, wr3, wr3 + 1024, el_ii, el_iu, er_ii, er_ui);
    k_prep_x<64, false><<<(NSRC + 255) / 256, 256, 0, stream>>>(x_user, NSRC, NDST0,
        wl3 + 1024, nullptr, wr3 + 512, nullptr, el_ui, nullptr, er_iu, nullptr);
    k_wt_all<64><<<3, 256, 0, stream>>>(W0, Wt3);

    {
        const int bprA = (NDST0 + 3) / 4;
        k_agg3<64><<<3 * bprA, 256, 0, stream>>>(cntA, bsrcA, el3, er3, x_item, x_user,
                                                 aggX, NDST0, bprA);
        const int bprG = NDST0 / 16;
        k_gemm3<64><<<3 * bprG, 256, 0, stream>>>(aggX, Wt3, out3, NDST0, bprG);
    }
    k_pool2<4><<<NDST0 / 16, 256, 0, stream>>>(out_iu, b0 + 256, out_iu, b0 + 256,
                                               x_user, 64, xu1, 128, 64, NDST0);
    k_pool2<8><<<NDST0 / 16, 256, 0, stream>>>(out_ii, b0, out_ui, b0 + 512,
                                               x_item, 64, xi1, 128, 64, NDST0);

    // ================= layer 2 (K=128) =================
    k_prep_wlr_all<<<6, 256, 0, stream>>>(W1, al1, ar1, wl3, wr3, 128);
    k_prep_x<128, true><<<(NDST0 + 255) / 256, 256, 0, stream>>>(xi1, NDST0, NDST1,
        wl3, wl3 + 512, wr3, wr3 + 1024, el_ii, el_iu, er_ii, er_ui);
    k_prep_x<128, false><<<(NDST0 + 255) / 256, 256, 0, stream>>>(xu1, NDST0, NDST1,
        wl3 + 1024, nullptr, wr3 + 512, nullptr, el_ui, nullptr, er_iu, nullptr);
    k_wt_all<128><<<3, 256, 0, stream>>>(W1, Wt3);

    {
        const int bprA = (NDST1 + 3) / 4;
        k_agg3<128><<<3 * bprA, 256, 0, stream>>>(cntB, bsrcB, el3, er3, xi1, xu1,
                                                  aggX, NDST1, bprA);
        const int bprG = NDST1 / 16;
        k_gemm3<128><<<3 * bprG, 256, 0, stream>>>(aggX, Wt3, out3, NDST1, bprG);
    }
    k_pool2<4><<<NDST1 / 16, 256, 0, stream>>>(out_iu, b1 + 256, out_iu, b1 + 256,
                                               xu1, 128, out, 192, 128, NDST1);
    k_pool2<8><<<NDST1 / 16, 256, 0, stream>>>(out_ii, b1, out_ui, b1 + 512,
                                               xi1, 128, out + (size_t)NDST1 * 192, 192, 128, NDST1);
}